// Round 8
// baseline (321.773 us; speedup 1.0000x reference)
//
#include <hip/hip_runtime.h>
#include <math.h>

using uint = unsigned int;
typedef _Float16 h2    __attribute__((ext_vector_type(2)));
typedef _Float16 f16x8 __attribute__((ext_vector_type(8)));
typedef float    f32x4 __attribute__((ext_vector_type(4)));

#define N_ATOMS 8192
#define NEDGE   262144
#define KNBR    32
#define NGAUSS  50
#define NLAYER  6
#define NB      32
#define GTAB    1024
#define DMAX    8.6603f
#define FCUT    10.0f
#define MB      1048576

// MFMA LDS geometry (uints). Stride 76: 16B-aligned frags, 2-way banks (free).
#define LSTRIDE 76
#define S_WT    0               // 128*76 = 9728
#define S_AS    9728            // 16*76 = 1216
#define S_TS    10944           // 1216
// table-build regions (table blocks only; disjoint blocks from setup work)
#define T_W1    0               // 4096
#define T_W2    4096            // 8192
#define T_RBF   12288           // 1024
#define T_HID   13312           // 2048
#define SMEM_N  15616           // 62.5 KB -> 2 blocks/CU

// wpack layout (uints): 18 mats 128x128 (c,kp): cf1 x6 | cf2 x6 | int x6; + ow1^T
#define OW1P_OFF 147456
#define WPACK_N  151552

__device__ __forceinline__ float ssp(float x) {
    return fmaxf(x, 0.0f) + log1pf(expf(-fabsf(x))) - 0.69314718055994531f;
}
__device__ __forceinline__ uint pack2(float a, float b) {
    union { h2 h; uint u; } x;
    h2 v; v.x = (_Float16)a; v.y = (_Float16)b; x.h = v; return x.u;
}
__device__ __forceinline__ h2 u2h(uint u) {
    union { uint u; h2 h; } x; x.u = u; return x.h;
}
__device__ __forceinline__ uint h2u(h2 h) {
    union { h2 h; uint u; } x; x.h = h; return x.u;
}
__device__ __forceinline__ float fdot2f(h2 a, h2 b, float c) {
#if __has_builtin(__builtin_amdgcn_fdot2)
    return __builtin_amdgcn_fdot2(a, b, c, false);
#else
    return fmaf((float)a.y, (float)b.y, fmaf((float)a.x, (float)b.x, c));
#endif
}

// copy pre-packed W^T (c,kp) 64-stride -> LDS stride-76
__device__ __forceinline__ void stage_cp(uint* sm, const uint* __restrict__ src,
                                         int n16, int tid) {
    for (int i = tid; i < n16; i += 256) {
        uint4 v = ((const uint4*)src)[i];
        *(uint4*)&sm[(i >> 4) * LSTRIDE + (i & 15) * 4] = v;
    }
}

// MFMA: D[16 rows][NCT*16 cols] = As(16x128) @ WT^T, cols base nb
template<int NCT>
__device__ __forceinline__ void run_gemm(const uint* sm, int as_off, int lane,
                                         int nb, f32x4* acc) {
    int m = lane & 15, q = lane >> 4;
    #pragma unroll
    for (int ks = 0; ks < 4; ++ks) {
        f16x8 a = *(const f16x8*)&sm[as_off + m * LSTRIDE + q * 4 + ks * 16];
        #pragma unroll
        for (int ct = 0; ct < NCT; ++ct) {
            f16x8 b = *(const f16x8*)&sm[S_WT + (nb + ct * 16 + m) * LSTRIDE + q * 4 + ks * 16];
            acc[ct] = __builtin_amdgcn_mfma_f32_16x16x32_f16(a, b, acc[ct], 0, 0, 0);
        }
    }
}

struct SArgs {
    const float *pos; const int *z; const int *ei; const int *dom;
    const float *emb;
    const float *cf1; const float *cf2w; const float *intw; const float *ow1;
    const float *mw1; const float *mb1; const float *mw2; const float *mb2;
    const float *dome; const float *fw1; const float *fb1;
    const float *fw2; const float *fb2; const float *bw; const float *bb;
    uint2 *epack; uint *tab2; float *h; uint *xA;
    float *gbias; uint *wpack; float *out; int out_size;
};

// ---------------------------------------------------------------------------
// blocks 0..511: zero-out + wcvt + epack + embed + x0 GEMM (+FiLM on 32..63)
// blocks 512..703: filter-table chunks (fp32 weights direct), tab2 interleaved
__global__ void __launch_bounds__(256) k_setup(SArgs a) {
    __shared__ __align__(16) uint sm[SMEM_N];
    const int tid = threadIdx.x, bid = blockIdx.x;
    const int lane = tid & 63, w = tid >> 6;
    const int m = lane & 15, q = lane >> 4;

    if (bid >= 512) {
        // ---- table chunk: layer l, 32 entries at base ----
        int c = bid - 512;
        int l = c >> 5;
        int base = (c & 31) * 32;
        for (int i = tid; i < 4096; i += 256) {       // W1p (kp<32, c)
            int kp = i >> 7, cc = i & 127;
            int g0 = 2 * kp;
            float va = (g0 < NGAUSS)     ? a.mw1[l*NGAUSS*128 + g0*128 + cc]     : 0.f;
            float vb = (g0 + 1 < NGAUSS) ? a.mw1[l*NGAUSS*128 + (g0+1)*128 + cc] : 0.f;
            sm[T_W1 + i] = pack2(va, vb);
        }
        for (int i = tid; i < 8192; i += 256) {       // W2p (kp<64, c)
            int kp = i >> 7, cc = i & 127;
            sm[T_W2 + i] = pack2(a.mw2[l*16384 + 2*kp*128 + cc],
                                 a.mw2[l*16384 + (2*kp+1)*128 + cc]);
        }
        const float delta = DMAX / (float)(GTAB - 1);
        const float gstep = FCUT / (float)(NGAUSS - 1);
        const float coeff = -0.5f / (gstep * gstep);
        for (int i = tid; i < 1024; i += 256) {
            int r = i >> 5, kp = i & 31;
            float dv = (float)(base + r) * delta;
            int g0 = 2 * kp;
            float v0 = 0.f, v1 = 0.f;
            if (g0 < NGAUSS)     { float t = dv - (float)g0 * gstep;     v0 = expf(coeff*t*t); }
            if (g0 + 1 < NGAUSS) { float t = dv - (float)(g0+1) * gstep; v1 = expf(coeff*t*t); }
            sm[T_RBF + i] = pack2(v0, v1);
        }
        __syncthreads();
        int tx = tid & 31, ty = tid >> 5, c0 = tx * 4, tr0 = ty * 4;
        float acc[4][4];
        #pragma unroll
        for (int i = 0; i < 4; ++i) { acc[i][0]=0.f; acc[i][1]=0.f; acc[i][2]=0.f; acc[i][3]=0.f; }
        #pragma unroll
        for (int oct = 0; oct < 8; ++oct) {
            int kp0 = oct * 4;
            uint4 w_[4];
            #pragma unroll
            for (int p = 0; p < 4; ++p) w_[p] = *(const uint4*)&sm[T_W1 + (kp0+p)*128 + c0];
            #pragma unroll
            for (int i = 0; i < 4; ++i) {
                uint4 av = *(const uint4*)&sm[T_RBF + (tr0+i)*32 + kp0];
                uint aa[4] = {av.x, av.y, av.z, av.w};
                #pragma unroll
                for (int p = 0; p < 4; ++p) {
                    h2 ap = u2h(aa[p]);
                    acc[i][0] = fdot2f(ap, u2h(w_[p].x), acc[i][0]);
                    acc[i][1] = fdot2f(ap, u2h(w_[p].y), acc[i][1]);
                    acc[i][2] = fdot2f(ap, u2h(w_[p].z), acc[i][2]);
                    acc[i][3] = fdot2f(ap, u2h(w_[p].w), acc[i][3]);
                }
            }
        }
        float4 b1v = *(const float4*)&a.mb1[l*128 + c0];
        #pragma unroll
        for (int i = 0; i < 4; ++i) {
            uint2 o;
            o.x = pack2(ssp(acc[i][0] + b1v.x), ssp(acc[i][1] + b1v.y));
            o.y = pack2(ssp(acc[i][2] + b1v.z), ssp(acc[i][3] + b1v.w));
            *(uint2*)&sm[T_HID + (tr0+i)*64 + (c0 >> 1)] = o;
        }
        __syncthreads();
        float acc2[4][4];
        #pragma unroll
        for (int i = 0; i < 4; ++i) { acc2[i][0]=0.f; acc2[i][1]=0.f; acc2[i][2]=0.f; acc2[i][3]=0.f; }
        #pragma unroll 4
        for (int oct = 0; oct < 16; ++oct) {
            int kp0 = oct * 4;
            uint4 w_[4];
            #pragma unroll
            for (int p = 0; p < 4; ++p) w_[p] = *(const uint4*)&sm[T_W2 + (kp0+p)*128 + c0];
            #pragma unroll
            for (int i = 0; i < 4; ++i) {
                uint4 av = *(const uint4*)&sm[T_HID + (tr0+i)*64 + kp0];
                uint aa[4] = {av.x, av.y, av.z, av.w};
                #pragma unroll
                for (int p = 0; p < 4; ++p) {
                    h2 ap = u2h(aa[p]);
                    acc2[i][0] = fdot2f(ap, u2h(w_[p].x), acc2[i][0]);
                    acc2[i][1] = fdot2f(ap, u2h(w_[p].y), acc2[i][1]);
                    acc2[i][2] = fdot2f(ap, u2h(w_[p].z), acc2[i][2]);
                    acc2[i][3] = fdot2f(ap, u2h(w_[p].w), acc2[i][3]);
                }
            }
        }
        float4 b2v = *(const float4*)&a.mb2[l*128 + c0];
        #pragma unroll
        for (int i = 0; i < 4; ++i) {
            int row = base + tr0 + i;
            float dv = (float)row * delta;
            float Cd = 0.5f * (cosf(dv * 0.3141592653589793f) + 1.0f);
            uint2 o;
            o.x = pack2((acc2[i][0] + b2v.x)*Cd, (acc2[i][1] + b2v.y)*Cd);
            o.y = pack2((acc2[i][2] + b2v.z)*Cd, (acc2[i][3] + b2v.w)*Cd);
            // tab2 entry e holds {row e (slots 0,1), row e+1 (slots 2,3)} per group
            *(uint2*)&a.tab2[(l*GTAB + row)*128 + tx*4] = o;
            if (row > 0)
                *(uint2*)&a.tab2[(l*GTAB + row - 1)*128 + tx*4 + 2] = o;
        }
        return;
    }

    const int gidx = bid * 256 + tid, gsz = 512 * 256;
    const int rowbase = bid * 16;

    for (int i = gidx; i < a.out_size; i += gsz) a.out[i] = 0.0f;

    // f16 weight pack (cf/int (c,kp) + ow1^T)
    for (int idx = gidx; idx < WPACK_N; idx += gsz) {
        if (idx < OW1P_OFF) {
            int mat = idx >> 13, e = idx & 8191;
            int kp = e >> 7, cc = e & 127;
            const float* src = (mat < 6) ? (a.cf1 + mat * 16384)
                            : (mat < 12) ? (a.cf2w + (mat - 6) * 16384)
                                         : (a.intw + (mat - 12) * 16384);
            a.wpack[mat * 8192 + cc * 64 + kp] =
                pack2(src[2 * kp * 128 + cc], src[(2 * kp + 1) * 128 + cc]);
        } else {
            int e = idx - OW1P_OFF;
            int kp = e >> 6, cc = e & 63;
            a.wpack[OW1P_OFF + cc * 64 + kp] =
                pack2(a.ow1[2 * kp * 64 + cc], a.ow1[(2 * kp + 1) * 64 + cc]);
        }
    }

    // epack: local 512 edges
    const float invdelta = (float)(GTAB - 1) / DMAX;
    #pragma unroll
    for (int t = 0; t < 2; ++t) {
        int e = rowbase * KNBR + t * 256 + tid;
        int s = a.ei[e], d = a.ei[NEDGE + e];
        float dx = a.pos[3*s] - a.pos[3*d];
        float dy = a.pos[3*s+1] - a.pos[3*d+1];
        float dz = a.pos[3*s+2] - a.pos[3*d+2];
        float dist = sqrtf(dx*dx + dy*dy + dz*dz);
        float u = dist * invdelta;
        int i0 = (int)u; i0 = (i0 < GTAB - 2) ? i0 : (GTAB - 2);
        float t2 = u - (float)i0;
        uint tb = pack2(t2, 0.0f) & 0xffffu;
        uint2 ep; ep.x = (uint)s; ep.y = (tb << 16) | (uint)i0;
        a.epack[e] = ep;
    }

    // embed -> h (f32) + As (f16)
    for (int i = tid; i < 1024; i += 256) {
        int r = i >> 6, f2 = i & 63;
        int zz = a.z[rowbase + r];
        float2 v = *(const float2*)&a.emb[zz * 128 + f2 * 2];
        *(float2*)&a.h[(rowbase + r) * 128 + f2 * 2] = v;
        sm[S_AS + r * LSTRIDE + f2] = pack2(v.x, v.y);
    }
    // WT <- cf1_0 (fp32 direct; wpack not yet visible within this kernel)
    for (int i = tid; i < 2048; i += 256) {
        int m4 = i >> 7, cc = i & 127;
        float v[8];
        #pragma unroll
        for (int j = 0; j < 8; ++j) v[j] = a.cf1[(8 * m4 + j) * 128 + cc];
        uint4 pk; pk.x = pack2(v[0], v[1]); pk.y = pack2(v[2], v[3]);
        pk.z = pack2(v[4], v[5]); pk.w = pack2(v[6], v[7]);
        *(uint4*)&sm[cc * LSTRIDE + m4 * 4] = pk;
    }
    __syncthreads();
    {   // x0 = h @ W1_0 -> xA
        f32x4 acc[2] = {{0,0,0,0},{0,0,0,0}};
        run_gemm<2>(sm, S_AS, lane, w * 32, acc);
        #pragma unroll
        for (int ct = 0; ct < 2; ++ct) {
            int n = w * 32 + ct * 16 + m;
            #pragma unroll
            for (int i = 0; i < 4; ++i) {
                float v = acc[ct][i];
                float u = __shfl_xor(v, 1, 64);
                if (!(lane & 1))
                    a.xA[(rowbase + q * 4 + i) * 64 + (n >> 1)] = pack2(v, u);
            }
        }
    }
    __syncthreads();
    if (bid >= 32 && bid < 64) {
        // FiLM beta sum (gamma path multiplies zeros), graph = bid-32
        int g = bid - 32;
        float* fs = (float*)sm;
        if (tid < 64) fs[tid] = a.dome[a.dom[g] * 64 + tid];
        __syncthreads();
        if (tid < 128) {
            float acc = a.fb1[tid];
            for (int i = 0; i < 64; ++i) acc = fmaf(fs[i], a.fw1[i*128 + tid], acc);
            fs[64 + tid] = fmaxf(acc, 0.0f);
        }
        __syncthreads();
        if (tid < 128) {
            float acc = a.fb2[tid];
            for (int i = 0; i < 128; ++i) acc = fmaf(fs[64+i], a.fw2[i*128 + tid], acc);
            fs[192 + tid] = acc;
        }
        __syncthreads();
        if (tid < 128) {
            float acc = a.bb[tid];
            for (int i = 0; i < 128; ++i) acc = fmaf(fs[192+i], a.bw[i*128 + tid], acc);
            #pragma unroll
            for (int off = 32; off > 0; off >>= 1) acc += __shfl_down(acc, off, 64);
            if ((tid & 63) == 0) fs[320 + (tid >> 6)] = acc;
        }
        __syncthreads();
        if (tid == 0) a.gbias[g] = fs[320] + fs[321];
    }
}

// ---------------------------------------------------------------------------
// edge gather, LDS-free. 1 wave per atom; 2 edges/iter (32 lanes each).
// tab2 dwordx4 gives both lerp endpoints in one load.
__global__ void __launch_bounds__(256) k_gather(
    const uint* __restrict__ xin, const uint* __restrict__ tab2l,
    const uint2* __restrict__ epack, uint* __restrict__ agg) {
    const int tid = threadIdx.x;
    const int lane = tid & 63;
    const int atom = blockIdx.x * 4 + (tid >> 6);
    const int side = lane >> 5, l5 = lane & 31;
    uint2 ep = epack[atom * KNBR + l5];
    h2 a0; a0.x = (_Float16)0; a0.y = (_Float16)0;
    h2 a1 = a0;
    #pragma unroll 4
    for (int k = 0; k < 16; ++k) {
        int e = 2 * k + side;
        uint s = __shfl(ep.x, e, 64);
        uint y = __shfl(ep.y, e, 64);
        int i0 = (int)(y & 0xffffu);
        uint th = y >> 16;
        h2 t2 = u2h(th | (th << 16));
        uint4 tv = *(const uint4*)&tab2l[i0 * 128 + l5 * 4];
        uint2 xv = *(const uint2*)&xin[s * 64 + l5 * 2];
        h2 w0 = u2h(tv.x) + t2 * (u2h(tv.z) - u2h(tv.x));
        h2 w1 = u2h(tv.y) + t2 * (u2h(tv.w) - u2h(tv.y));
        a0 = a0 + u2h(xv.x) * w0;
        a1 = a1 + u2h(xv.y) * w1;
    }
    uint u0 = h2u(a0), u1 = h2u(a1);
    uint p0 = __shfl_xor(u0, 32, 64), p1 = __shfl_xor(u1, 32, 64);
    if (side == 0) {
        h2 r0 = u2h(u0) + u2h(p0), r1 = u2h(u1) + u2h(p1);
        uint2 o; o.x = h2u(r0); o.y = h2u(r1);
        *(uint2*)&agg[atom * 64 + l5 * 2] = o;
    }
}

// ---------------------------------------------------------------------------
// GEMM part of a layer. W3/W1n/h prefetched to registers at start so only
// one L2 round-trip sits on the serial path.
template<bool LAST>
__global__ void __launch_bounds__(256) k_gemmL(
    float* __restrict__ h, const uint* __restrict__ agg, uint* __restrict__ xout,
    const uint* __restrict__ w2p, const uint* __restrict__ w3p,
    const uint* __restrict__ w1np,
    const float* __restrict__ b2, const float* __restrict__ b3,
    const float* __restrict__ ob1, const float* __restrict__ ow2,
    const float* __restrict__ ob2, const float* __restrict__ gbias,
    float* __restrict__ out) {
    __shared__ __align__(16) uint sm[S_TS + 1216];   // 48.6 KB -> 3 blocks/CU
    const int tid = threadIdx.x, bid = blockIdx.x;
    const int lane = tid & 63, w = tid >> 6;
    const int m = lane & 15, q = lane >> 4;
    const int rowbase = bid * 16;

    // --- prefetch everything global in one burst ---
    constexpr int NW1 = LAST ? 4 : 8;
    uint4 w3r[8], w1r[NW1];
    #pragma unroll
    for (int j = 0; j < 8; ++j) w3r[j] = ((const uint4*)w3p)[tid + 256 * j];
    #pragma unroll
    for (int j = 0; j < NW1; ++j) w1r[j] = ((const uint4*)w1np)[tid + 256 * j];
    float hr[2][4];
    #pragma unroll
    for (int ct = 0; ct < 2; ++ct)
        #pragma unroll
        for (int i = 0; i < 4; ++i)
            hr[ct][i] = h[(rowbase + q * 4 + i) * 128 + w * 32 + ct * 16 + m];
    stage_cp(sm, w2p, 2048, tid);                         // W2 -> LDS
    {   uint4 v = ((const uint4*)(agg + rowbase * 64))[tid];
        *(uint4*)&sm[S_AS + (tid >> 4) * LSTRIDE + (tid & 15) * 4] = v; }
    __syncthreads();
    {   // Ts = ssp(As @ W2 + b2)
        f32x4 acc[2] = {{0,0,0,0},{0,0,0,0}};
        run_gemm<2>(sm, S_AS, lane, w * 32, acc);
        #pragma unroll
        for (int ct = 0; ct < 2; ++ct) {
            int n = w * 32 + ct * 16 + m;
            float bv = b2[n];
            #pragma unroll
            for (int i = 0; i < 4; ++i) {
                float v = ssp(acc[ct][i] + bv);
                float u = __shfl_xor(v, 1, 64);
                if (!(lane & 1))
                    sm[S_TS + (q * 4 + i) * LSTRIDE + (n >> 1)] = pack2(v, u);
            }
        }
    }
    __syncthreads();
    #pragma unroll
    for (int j = 0; j < 8; ++j) {                         // W3 regs -> LDS
        int i = tid + 256 * j;
        *(uint4*)&sm[(i >> 4) * LSTRIDE + (i & 15) * 4] = w3r[j];
    }
    __syncthreads();
    {   // h += Ts @ W3 + b3 ; As <- h_new
        f32x4 acc[2] = {{0,0,0,0},{0,0,0,0}};
        run_gemm<2>(sm, S_TS, lane, w * 32, acc);
        #pragma unroll
        for (int ct = 0; ct < 2; ++ct) {
            int n = w * 32 + ct * 16 + m;
            float bv = b3[n];
            #pragma unroll
            for (int i = 0; i < 4; ++i) {
                int r = rowbase + q * 4 + i;
                float hv = hr[ct][i] + acc[ct][i] + bv;
                h[r * 128 + n] = hv;
                float u = __shfl_xor(hv, 1, 64);
                if (!(lane & 1))
                    sm[S_AS + (q * 4 + i) * LSTRIDE + (n >> 1)] = pack2(hv, u);
            }
        }
    }
    __syncthreads();
    #pragma unroll
    for (int j = 0; j < NW1; ++j) {                       // W1n regs -> LDS
        int i = tid + 256 * j;
        *(uint4*)&sm[(i >> 4) * LSTRIDE + (i & 15) * 4] = w1r[j];
    }
    __syncthreads();
    if (!LAST) {
        f32x4 acc[2] = {{0,0,0,0},{0,0,0,0}};
        run_gemm<2>(sm, S_AS, lane, w * 32, acc);
        #pragma unroll
        for (int ct = 0; ct < 2; ++ct) {
            int n = w * 32 + ct * 16 + m;
            #pragma unroll
            for (int i = 0; i < 4; ++i) {
                float v = acc[ct][i];
                float u = __shfl_xor(v, 1, 64);
                if (!(lane & 1))
                    xout[(rowbase + q * 4 + i) * 64 + (n >> 1)] = pack2(v, u);
            }
        }
    } else {
        f32x4 acc[1] = {{0,0,0,0}};
        run_gemm<1>(sm, S_AS, lane, w * 16, acc);
        int n = w * 16 + m;
        float b1v = ob1[n], w2v = ow2[n];
        float part = 0.f;
        #pragma unroll
        for (int i = 0; i < 4; ++i) part += ssp(acc[0][i] + b1v) * w2v;
        #pragma unroll
        for (int mm = 1; mm < 64; mm <<= 1) part += __shfl_xor(part, mm, 64);
        float* fs = (float*)&sm[S_TS];
        if (lane == 0) fs[w] = part;
        __syncthreads();
        if (tid == 0) {
            float bsum = fs[0] + fs[1] + fs[2] + fs[3] + 16.0f * ob2[0];
            float add = 32.0f * bsum;
            if ((bid & 15) == 0) {
                float sb = 0.f;
                for (int j = 0; j < NB; ++j) sb += gbias[j];
                add += sb;
            }
            atomicAdd(&out[bid >> 4], add);
        }
    }
}

// ---------------------------------------------------------------------------
extern "C" void kernel_launch(void* const* d_in, const int* in_sizes, int n_in,
                              void* d_out, int out_size, void* d_ws, size_t ws_size,
                              hipStream_t stream) {
    SArgs a;
    a.pos  = (const float*)d_in[0];
    a.z    = (const int*)d_in[1];
    a.ei   = (const int*)d_in[3];
    a.dom  = (const int*)d_in[4];
    a.emb  = (const float*)d_in[5];
    a.mw1  = (const float*)d_in[6];
    a.mb1  = (const float*)d_in[7];
    a.mw2  = (const float*)d_in[8];
    a.mb2  = (const float*)d_in[9];
    a.cf1  = (const float*)d_in[10];
    a.cf2w = (const float*)d_in[11];
    const float* cf2b = (const float*)d_in[12];
    a.intw = (const float*)d_in[13];
    const float* intb = (const float*)d_in[14];
    a.ow1  = (const float*)d_in[15];
    const float* ob1  = (const float*)d_in[16];
    const float* ow2  = (const float*)d_in[17];
    const float* ob2  = (const float*)d_in[18];
    a.dome = (const float*)d_in[19];
    a.fw1  = (const float*)d_in[20];
    a.fb1  = (const float*)d_in[21];
    a.fw2  = (const float*)d_in[22];
    a.fb2  = (const float*)d_in[23];
    a.bw   = (const float*)d_in[26];
    a.bb   = (const float*)d_in[27];

    char* ws = (char*)d_ws;
    a.epack  = (uint2*)(ws + 0);               // 2 MB
    a.tab2   = (uint*)(ws + 2*MB);             // 3 MB (interleaved pairs)
    a.h      = (float*)(ws + 5*MB);            // 4 MB
    a.xA     = (uint*)(ws + 9*MB);             // 2 MB
    uint* xB = (uint*)(ws + 11*MB);            // 2 MB
    uint* agg= (uint*)(ws + 13*MB);            // 2 MB
    a.gbias  = (float*)(ws + 15*MB);           // 128 B
    a.wpack  = (uint*)(ws + 15*MB + 4096);     // 606 KB
    a.out = (float*)d_out;
    a.out_size = out_size;

    k_setup<<<704, 256, 0, stream>>>(a);

    const uint* xr = a.xA;
    uint* xw = xB;
    for (int l = 0; l < NLAYER; ++l) {
        k_gather<<<N_ATOMS/4, 256, 0, stream>>>(xr, a.tab2 + l*GTAB*128, a.epack, agg);
        const uint* w2p = a.wpack + (6 + l) * 8192;
        const uint* w3p = a.wpack + (12 + l) * 8192;
        if (l < NLAYER - 1) {
            k_gemmL<false><<<512, 256, 0, stream>>>(
                a.h, agg, xw, w2p, w3p, a.wpack + (l + 1) * 8192,
                cf2b + l*128, intb + l*128, ob1, ow2, ob2, a.gbias, a.out);
        } else {
            k_gemmL<true><<<512, 256, 0, stream>>>(
                a.h, agg, xw, w2p, w3p, a.wpack + OW1P_OFF,
                cf2b + l*128, intb + l*128, ob1, ow2, ob2, a.gbias, a.out);
        }
        const uint* tmp = xr; xr = xw; xw = (uint*)tmp;
    }
}

// Round 9
// 314.416 us; speedup vs baseline: 1.0234x; 1.0234x over previous
//
#include <hip/hip_runtime.h>
#include <math.h>

using uint = unsigned int;
typedef _Float16 h2    __attribute__((ext_vector_type(2)));
typedef _Float16 f16x8 __attribute__((ext_vector_type(8)));
typedef float    f32x4 __attribute__((ext_vector_type(4)));

#define N_ATOMS 8192
#define NEDGE   262144
#define KNBR    32
#define NGAUSS  50
#define NLAYER  6
#define NB      32
#define GTAB    1024
#define DMAX    8.6603f
#define FCUT    10.0f
#define MB      1048576

// MFMA LDS geometry (uints). Stride 76: 16B-aligned frags, 2-way banks (free).
#define LSTRIDE 76
#define S_WT    0               // 128*76 = 9728
#define S_AS    9728            // 16*76 = 1216
#define S_TS    10944           // 1216
#define GEMM_SMEM 12160         // 48.6 KB -> 3 blocks/CU

// table kernel LDS (uints)
#define T_W1    0               // 4096
#define T_W2    4096            // 8192
#define T_RBF   12288           // 1024
#define T_HID   13312           // 2048
#define TAB_SMEM 15360

// wpack layout (uints)
#define OW1P_OFF 147456         // 18 mats 128x128 (c,kp): cf1 x6 | cf2 x6 | int x6
#define M1_OFF   151552         // + ow1^T 64x64 (c,kp)
#define M2_OFF   176128         // + mlp_w1 f16 (kp,c) x6
#define WPACK_N  225280         // + mlp_w2 f16 (kp,c) x6

__device__ __forceinline__ float ssp(float x) {
    return fmaxf(x, 0.0f) + log1pf(expf(-fabsf(x))) - 0.69314718055994531f;
}
__device__ __forceinline__ uint pack2(float a, float b) {
    union { h2 h; uint u; } x;
    h2 v; v.x = (_Float16)a; v.y = (_Float16)b; x.h = v; return x.u;
}
__device__ __forceinline__ h2 u2h(uint u) {
    union { uint u; h2 h; } x; x.u = u; return x.h;
}
__device__ __forceinline__ uint h2u(h2 h) {
    union { h2 h; uint u; } x; x.h = h; return x.u;
}
__device__ __forceinline__ float fdot2f(h2 a, h2 b, float c) {
#if __has_builtin(__builtin_amdgcn_fdot2)
    return __builtin_amdgcn_fdot2(a, b, c, false);
#else
    return fmaf((float)a.y, (float)b.y, fmaf((float)a.x, (float)b.x, c));
#endif
}

// copy pre-packed W^T (c,kp) 64-stride -> LDS stride-76
__device__ __forceinline__ void stage_cp(uint* sm, const uint* __restrict__ src,
                                         int n16, int tid) {
    for (int i = tid; i < n16; i += 256) {
        uint4 v = ((const uint4*)src)[i];
        *(uint4*)&sm[(i >> 4) * LSTRIDE + (i & 15) * 4] = v;
    }
}

// MFMA: D[16 rows][NCT*16 cols] = As(16x128) @ WT^T, cols base nb
template<int NCT>
__device__ __forceinline__ void run_gemm(const uint* sm, int as_off, int lane,
                                         int nb, f32x4* acc) {
    int m = lane & 15, q = lane >> 4;
    #pragma unroll
    for (int ks = 0; ks < 4; ++ks) {
        f16x8 a = *(const f16x8*)&sm[as_off + m * LSTRIDE + q * 4 + ks * 16];
        #pragma unroll
        for (int ct = 0; ct < NCT; ++ct) {
            f16x8 b = *(const f16x8*)&sm[S_WT + (nb + ct * 16 + m) * LSTRIDE + q * 4 + ks * 16];
            acc[ct] = __builtin_amdgcn_mfma_f32_16x16x32_f16(a, b, acc[ct], 0, 0, 0);
        }
    }
}

struct SArgs {
    const float *pos; const int *z; const int *ei; const int *dom;
    const float *emb;
    const float *cf1; const float *cf2w; const float *intw; const float *ow1;
    const float *mw1; const float *mw2;
    const float *dome; const float *fw1; const float *fb1;
    const float *fw2; const float *fb2; const float *bw; const float *bb;
    uint2 *epack; float *h; uint *xA;
    float *gbias; uint *wpack; float *out; int out_size;
};

// ---------------------------------------------------------------------------
// setup: zero-out + wcvt + epack + embed + x0 GEMM + film (blocks 32..63)
__global__ void __launch_bounds__(256) k_setup(SArgs a) {
    __shared__ __align__(16) uint sm[S_AS + 1216];
    const int tid = threadIdx.x, bid = blockIdx.x;
    const int gidx = bid * 256 + tid, gsz = 512 * 256;
    const int lane = tid & 63, w = tid >> 6;
    const int m = lane & 15, q = lane >> 4;
    const int rowbase = bid * 16;

    for (int i = gidx; i < a.out_size; i += gsz) a.out[i] = 0.0f;

    // f16 weight pack
    for (int idx = gidx; idx < WPACK_N; idx += gsz) {
        if (idx < OW1P_OFF) {
            int mat = idx >> 13, e = idx & 8191;
            int kp = e >> 7, cc = e & 127;
            const float* src = (mat < 6) ? (a.cf1 + mat * 16384)
                            : (mat < 12) ? (a.cf2w + (mat - 6) * 16384)
                                         : (a.intw + (mat - 12) * 16384);
            a.wpack[mat * 8192 + cc * 64 + kp] =
                pack2(src[2 * kp * 128 + cc], src[(2 * kp + 1) * 128 + cc]);
        } else if (idx < M1_OFF) {
            int e = idx - OW1P_OFF;
            int kp = e >> 6, cc = e & 63;
            a.wpack[OW1P_OFF + cc * 64 + kp] =
                pack2(a.ow1[2 * kp * 64 + cc], a.ow1[(2 * kp + 1) * 64 + cc]);
        } else if (idx < M2_OFF) {
            int e = idx - M1_OFF;
            int l = e >> 12, r = e & 4095;
            int kp = r >> 7, cc = r & 127;
            int g0 = 2 * kp;
            float va = (g0 < NGAUSS)     ? a.mw1[l*NGAUSS*128 + g0*128 + cc]     : 0.f;
            float vb = (g0 + 1 < NGAUSS) ? a.mw1[l*NGAUSS*128 + (g0+1)*128 + cc] : 0.f;
            a.wpack[idx] = pack2(va, vb);
        } else {
            int e = idx - M2_OFF;
            int l = e >> 13, r = e & 8191;
            int kp = r >> 7, cc = r & 127;
            a.wpack[idx] = pack2(a.mw2[l*16384 + 2*kp*128 + cc],
                                 a.mw2[l*16384 + (2*kp+1)*128 + cc]);
        }
    }

    // epack: local 512 edges
    const float invdelta = (float)(GTAB - 1) / DMAX;
    #pragma unroll
    for (int t = 0; t < 2; ++t) {
        int e = rowbase * KNBR + t * 256 + tid;
        int s = a.ei[e], d = a.ei[NEDGE + e];
        float dx = a.pos[3*s] - a.pos[3*d];
        float dy = a.pos[3*s+1] - a.pos[3*d+1];
        float dz = a.pos[3*s+2] - a.pos[3*d+2];
        float dist = sqrtf(dx*dx + dy*dy + dz*dz);
        float u = dist * invdelta;
        int i0 = (int)u; i0 = (i0 < GTAB - 2) ? i0 : (GTAB - 2);
        float t2 = u - (float)i0;
        uint tb = pack2(t2, 0.0f) & 0xffffu;
        uint2 ep; ep.x = (uint)s; ep.y = (tb << 16) | (uint)i0;
        a.epack[e] = ep;
    }

    // embed -> h (f32) + As (f16)
    for (int i = tid; i < 1024; i += 256) {
        int r = i >> 6, f2 = i & 63;
        int zz = a.z[rowbase + r];
        float2 v = *(const float2*)&a.emb[zz * 128 + f2 * 2];
        *(float2*)&a.h[(rowbase + r) * 128 + f2 * 2] = v;
        sm[S_AS + r * LSTRIDE + f2] = pack2(v.x, v.y);
    }
    // WT <- cf1_0 (fp32 direct; wpack not yet visible within this kernel)
    for (int i = tid; i < 2048; i += 256) {
        int m4 = i >> 7, cc = i & 127;
        float v[8];
        #pragma unroll
        for (int j = 0; j < 8; ++j) v[j] = a.cf1[(8 * m4 + j) * 128 + cc];
        uint4 pk; pk.x = pack2(v[0], v[1]); pk.y = pack2(v[2], v[3]);
        pk.z = pack2(v[4], v[5]); pk.w = pack2(v[6], v[7]);
        *(uint4*)&sm[cc * LSTRIDE + m4 * 4] = pk;
    }
    __syncthreads();
    {   // x0 = h @ W1_0 -> xA
        f32x4 acc[2] = {{0,0,0,0},{0,0,0,0}};
        run_gemm<2>(sm, S_AS, lane, w * 32, acc);
        #pragma unroll
        for (int ct = 0; ct < 2; ++ct) {
            int n = w * 32 + ct * 16 + m;
            #pragma unroll
            for (int i = 0; i < 4; ++i) {
                float v = acc[ct][i];
                float u = __shfl_xor(v, 1, 64);
                if (!(lane & 1))
                    a.xA[(rowbase + q * 4 + i) * 64 + (n >> 1)] = pack2(v, u);
            }
        }
    }
    __syncthreads();
    if (bid >= 32 && bid < 64) {
        // FiLM beta sum (gamma path multiplies zeros), graph = bid-32
        int g = bid - 32;
        float* fs = (float*)sm;
        if (tid < 64) fs[tid] = a.dome[a.dom[g] * 64 + tid];
        __syncthreads();
        if (tid < 128) {
            float acc = a.fb1[tid];
            for (int i = 0; i < 64; ++i) acc = fmaf(fs[i], a.fw1[i*128 + tid], acc);
            fs[64 + tid] = fmaxf(acc, 0.0f);
        }
        __syncthreads();
        if (tid < 128) {
            float acc = a.fb2[tid];
            for (int i = 0; i < 128; ++i) acc = fmaf(fs[64+i], a.fw2[i*128 + tid], acc);
            fs[192 + tid] = acc;
        }
        __syncthreads();
        if (tid < 128) {
            float acc = a.bb[tid];
            for (int i = 0; i < 128; ++i) acc = fmaf(fs[192+i], a.bw[i*128 + tid], acc);
            #pragma unroll
            for (int off = 32; off > 0; off >>= 1) acc += __shfl_down(acc, off, 64);
            if ((tid & 63) == 0) fs[320 + (tid >> 6)] = acc;
        }
        __syncthreads();
        if (tid == 0) a.gbias[g] = fs[320] + fs[321];
    }
}

// ---------------------------------------------------------------------------
// filter tables from f16 wpack: 192 blocks = 6 layers x 32 chunks x 32 rows.
// Writes interleaved tab2: entry e holds rows {e, e+1} (16B per 2-feature group).
__global__ void __launch_bounds__(256) k_table(
    const uint* __restrict__ wpack, const float* __restrict__ mb1,
    const float* __restrict__ mb2, uint* __restrict__ tab2) {
    __shared__ __align__(16) uint sm[TAB_SMEM];
    const int tid = threadIdx.x;
    const int l = blockIdx.x >> 5;
    const int base = (blockIdx.x & 31) * 32;
    { const uint4* s4 = (const uint4*)(wpack + M1_OFF + l*4096);
      uint4* d4 = (uint4*)&sm[T_W1];
      for (int i = tid; i < 1024; i += 256) d4[i] = s4[i]; }
    { const uint4* s4 = (const uint4*)(wpack + M2_OFF + l*8192);
      uint4* d4 = (uint4*)&sm[T_W2];
      for (int i = tid; i < 2048; i += 256) d4[i] = s4[i]; }
    const float delta = DMAX / (float)(GTAB - 1);
    const float gstep = FCUT / (float)(NGAUSS - 1);
    const float coeff = -0.5f / (gstep * gstep);
    for (int i = tid; i < 1024; i += 256) {
        int r = i >> 5, kp = i & 31;
        float dv = (float)(base + r) * delta;
        int g0 = 2 * kp;
        float v0 = 0.f, v1 = 0.f;
        if (g0 < NGAUSS)     { float t = dv - (float)g0 * gstep;     v0 = expf(coeff*t*t); }
        if (g0 + 1 < NGAUSS) { float t = dv - (float)(g0+1) * gstep; v1 = expf(coeff*t*t); }
        sm[T_RBF + i] = pack2(v0, v1);
    }
    __syncthreads();
    int tx = tid & 31, ty = tid >> 5, c0 = tx * 4, tr0 = ty * 4;
    float acc[4][4];
    #pragma unroll
    for (int i = 0; i < 4; ++i) { acc[i][0]=0.f; acc[i][1]=0.f; acc[i][2]=0.f; acc[i][3]=0.f; }
    #pragma unroll
    for (int oct = 0; oct < 8; ++oct) {              // stage 1: K=50 (32 pairs)
        int kp0 = oct * 4;
        uint4 w_[4];
        #pragma unroll
        for (int p = 0; p < 4; ++p) w_[p] = *(const uint4*)&sm[T_W1 + (kp0+p)*128 + c0];
        #pragma unroll
        for (int i = 0; i < 4; ++i) {
            uint4 av = *(const uint4*)&sm[T_RBF + (tr0+i)*32 + kp0];
            uint aa[4] = {av.x, av.y, av.z, av.w};
            #pragma unroll
            for (int p = 0; p < 4; ++p) {
                h2 ap = u2h(aa[p]);
                acc[i][0] = fdot2f(ap, u2h(w_[p].x), acc[i][0]);
                acc[i][1] = fdot2f(ap, u2h(w_[p].y), acc[i][1]);
                acc[i][2] = fdot2f(ap, u2h(w_[p].z), acc[i][2]);
                acc[i][3] = fdot2f(ap, u2h(w_[p].w), acc[i][3]);
            }
        }
    }
    float4 b1v = *(const float4*)&mb1[l*128 + c0];
    #pragma unroll
    for (int i = 0; i < 4; ++i) {
        uint2 o;
        o.x = pack2(ssp(acc[i][0] + b1v.x), ssp(acc[i][1] + b1v.y));
        o.y = pack2(ssp(acc[i][2] + b1v.z), ssp(acc[i][3] + b1v.w));
        *(uint2*)&sm[T_HID + (tr0+i)*64 + (c0 >> 1)] = o;
    }
    __syncthreads();
    float acc2[4][4];
    #pragma unroll
    for (int i = 0; i < 4; ++i) { acc2[i][0]=0.f; acc2[i][1]=0.f; acc2[i][2]=0.f; acc2[i][3]=0.f; }
    #pragma unroll 4
    for (int oct = 0; oct < 16; ++oct) {             // stage 2: K=128
        int kp0 = oct * 4;
        uint4 w_[4];
        #pragma unroll
        for (int p = 0; p < 4; ++p) w_[p] = *(const uint4*)&sm[T_W2 + (kp0+p)*128 + c0];
        #pragma unroll
        for (int i = 0; i < 4; ++i) {
            uint4 av = *(const uint4*)&sm[T_HID + (tr0+i)*64 + kp0];
            uint aa[4] = {av.x, av.y, av.z, av.w};
            #pragma unroll
            for (int p = 0; p < 4; ++p) {
                h2 ap = u2h(aa[p]);
                acc2[i][0] = fdot2f(ap, u2h(w_[p].x), acc2[i][0]);
                acc2[i][1] = fdot2f(ap, u2h(w_[p].y), acc2[i][1]);
                acc2[i][2] = fdot2f(ap, u2h(w_[p].z), acc2[i][2]);
                acc2[i][3] = fdot2f(ap, u2h(w_[p].w), acc2[i][3]);
            }
        }
    }
    float4 b2v = *(const float4*)&mb2[l*128 + c0];
    #pragma unroll
    for (int i = 0; i < 4; ++i) {
        int row = base + tr0 + i;
        float dv = (float)row * delta;
        float Cd = 0.5f * (cosf(dv * 0.3141592653589793f) + 1.0f);
        uint2 o;
        o.x = pack2((acc2[i][0] + b2v.x)*Cd, (acc2[i][1] + b2v.y)*Cd);
        o.y = pack2((acc2[i][2] + b2v.z)*Cd, (acc2[i][3] + b2v.w)*Cd);
        *(uint2*)&tab2[(l*GTAB + row)*128 + tx*4] = o;          // own row, slots 0,1
        if (row > 0)
            *(uint2*)&tab2[(l*GTAB + row - 1)*128 + tx*4 + 2] = o;  // prev row, slots 2,3
    }
}

// ---------------------------------------------------------------------------
// edge gather, LDS-free. 1 wave per atom; 2 edges/iter (32 lanes each).
// tab2 dwordx4 gives both lerp endpoints in one load.
__global__ void __launch_bounds__(256) k_gather(
    const uint* __restrict__ xin, const uint* __restrict__ tab2l,
    const uint2* __restrict__ epack, uint* __restrict__ agg) {
    const int tid = threadIdx.x;
    const int lane = tid & 63;
    const int atom = blockIdx.x * 4 + (tid >> 6);
    const int side = lane >> 5, l5 = lane & 31;
    uint2 ep = epack[atom * KNBR + l5];
    h2 a0; a0.x = (_Float16)0; a0.y = (_Float16)0;
    h2 a1 = a0;
    #pragma unroll 4
    for (int k = 0; k < 16; ++k) {
        int e = 2 * k + side;
        uint s = __shfl(ep.x, e, 64);
        uint y = __shfl(ep.y, e, 64);
        int i0 = (int)(y & 0xffffu);
        uint th = y >> 16;
        h2 t2 = u2h(th | (th << 16));
        uint4 tv = *(const uint4*)&tab2l[i0 * 128 + l5 * 4];
        uint2 xv = *(const uint2*)&xin[s * 64 + l5 * 2];
        h2 w0 = u2h(tv.x) + t2 * (u2h(tv.z) - u2h(tv.x));
        h2 w1 = u2h(tv.y) + t2 * (u2h(tv.w) - u2h(tv.y));
        a0 = a0 + u2h(xv.x) * w0;
        a1 = a1 + u2h(xv.y) * w1;
    }
    uint u0 = h2u(a0), u1 = h2u(a1);
    uint p0 = __shfl_xor(u0, 32, 64), p1 = __shfl_xor(u1, 32, 64);
    if (side == 0) {
        h2 r0 = u2h(u0) + u2h(p0), r1 = u2h(u1) + u2h(p1);
        uint2 o; o.x = h2u(r0); o.y = h2u(r1);
        *(uint2*)&agg[atom * 64 + l5 * 2] = o;
    }
}

// ---------------------------------------------------------------------------
// GEMM part of a layer. W3/W1n/h prefetched to registers at start so only
// one L2 round-trip sits on the serial path.
template<bool LAST>
__global__ void __launch_bounds__(256) k_gemmL(
    float* __restrict__ h, const uint* __restrict__ agg, uint* __restrict__ xout,
    const uint* __restrict__ w2p, const uint* __restrict__ w3p,
    const uint* __restrict__ w1np,
    const float* __restrict__ b2, const float* __restrict__ b3,
    const float* __restrict__ ob1, const float* __restrict__ ow2,
    const float* __restrict__ ob2, const float* __restrict__ gbias,
    float* __restrict__ out) {
    __shared__ __align__(16) uint sm[GEMM_SMEM];   // 48.6 KB -> 3 blocks/CU
    const int tid = threadIdx.x, bid = blockIdx.x;
    const int lane = tid & 63, w = tid >> 6;
    const int m = lane & 15, q = lane >> 4;
    const int rowbase = bid * 16;

    // --- prefetch everything global in one burst ---
    constexpr int NW1 = LAST ? 4 : 8;
    uint4 w3r[8], w1r[NW1];
    #pragma unroll
    for (int j = 0; j < 8; ++j) w3r[j] = ((const uint4*)w3p)[tid + 256 * j];
    #pragma unroll
    for (int j = 0; j < NW1; ++j) w1r[j] = ((const uint4*)w1np)[tid + 256 * j];
    float hr[2][4];
    #pragma unroll
    for (int ct = 0; ct < 2; ++ct)
        #pragma unroll
        for (int i = 0; i < 4; ++i)
            hr[ct][i] = h[(rowbase + q * 4 + i) * 128 + w * 32 + ct * 16 + m];
    stage_cp(sm, w2p, 2048, tid);                         // W2 -> LDS
    {   uint4 v = ((const uint4*)(agg + rowbase * 64))[tid];
        *(uint4*)&sm[S_AS + (tid >> 4) * LSTRIDE + (tid & 15) * 4] = v; }
    __syncthreads();
    {   // Ts = ssp(As @ W2 + b2)
        f32x4 acc[2] = {{0,0,0,0},{0,0,0,0}};
        run_gemm<2>(sm, S_AS, lane, w * 32, acc);
        #pragma unroll
        for (int ct = 0; ct < 2; ++ct) {
            int n = w * 32 + ct * 16 + m;
            float bv = b2[n];
            #pragma unroll
            for (int i = 0; i < 4; ++i) {
                float v = ssp(acc[ct][i] + bv);
                float u = __shfl_xor(v, 1, 64);
                if (!(lane & 1))
                    sm[S_TS + (q * 4 + i) * LSTRIDE + (n >> 1)] = pack2(v, u);
            }
        }
    }
    __syncthreads();
    #pragma unroll
    for (int j = 0; j < 8; ++j) {                         // W3 regs -> LDS
        int i = tid + 256 * j;
        *(uint4*)&sm[(i >> 4) * LSTRIDE + (i & 15) * 4] = w3r[j];
    }
    __syncthreads();
    {   // h += Ts @ W3 + b3 ; As <- h_new
        f32x4 acc[2] = {{0,0,0,0},{0,0,0,0}};
        run_gemm<2>(sm, S_TS, lane, w * 32, acc);
        #pragma unroll
        for (int ct = 0; ct < 2; ++ct) {
            int n = w * 32 + ct * 16 + m;
            float bv = b3[n];
            #pragma unroll
            for (int i = 0; i < 4; ++i) {
                int r = rowbase + q * 4 + i;
                float hv = hr[ct][i] + acc[ct][i] + bv;
                h[r * 128 + n] = hv;
                float u = __shfl_xor(hv, 1, 64);
                if (!(lane & 1))
                    sm[S_AS + (q * 4 + i) * LSTRIDE + (n >> 1)] = pack2(hv, u);
            }
        }
    }
    __syncthreads();
    #pragma unroll
    for (int j = 0; j < NW1; ++j) {                       // W1n regs -> LDS
        int i = tid + 256 * j;
        *(uint4*)&sm[(i >> 4) * LSTRIDE + (i & 15) * 4] = w1r[j];
    }
    __syncthreads();
    if (!LAST) {
        f32x4 acc[2] = {{0,0,0,0},{0,0,0,0}};
        run_gemm<2>(sm, S_AS, lane, w * 32, acc);
        #pragma unroll
        for (int ct = 0; ct < 2; ++ct) {
            int n = w * 32 + ct * 16 + m;
            #pragma unroll
            for (int i = 0; i < 4; ++i) {
                float v = acc[ct][i];
                float u = __shfl_xor(v, 1, 64);
                if (!(lane & 1))
                    xout[(rowbase + q * 4 + i) * 64 + (n >> 1)] = pack2(v, u);
            }
        }
    } else {
        f32x4 acc[1] = {{0,0,0,0}};
        run_gemm<1>(sm, S_AS, lane, w * 16, acc);
        int n = w * 16 + m;
        float b1v = ob1[n], w2v = ow2[n];
        float part = 0.f;
        #pragma unroll
        for (int i = 0; i < 4; ++i) part += ssp(acc[0][i] + b1v) * w2v;
        #pragma unroll
        for (int mm = 1; mm < 64; mm <<= 1) part += __shfl_xor(part, mm, 64);
        float* fs = (float*)&sm[S_TS];
        if (lane == 0) fs[w] = part;
        __syncthreads();
        if (tid == 0) {
            float bsum = fs[0] + fs[1] + fs[2] + fs[3] + 16.0f * ob2[0];
            float add = 32.0f * bsum;
            if ((bid & 15) == 0) {
                float sb = 0.f;
                for (int j = 0; j < NB; ++j) sb += gbias[j];
                add += sb;
            }
            atomicAdd(&out[bid >> 4], add);
        }
    }
}

// ---------------------------------------------------------------------------
extern "C" void kernel_launch(void* const* d_in, const int* in_sizes, int n_in,
                              void* d_out, int out_size, void* d_ws, size_t ws_size,
                              hipStream_t stream) {
    SArgs a;
    a.pos  = (const float*)d_in[0];
    a.z    = (const int*)d_in[1];
    a.ei   = (const int*)d_in[3];
    a.dom  = (const int*)d_in[4];
    a.emb  = (const float*)d_in[5];
    a.mw1  = (const float*)d_in[6];
    const float* mb1 = (const float*)d_in[7];
    a.mw2  = (const float*)d_in[8];
    const float* mb2 = (const float*)d_in[9];
    a.cf1  = (const float*)d_in[10];
    a.cf2w = (const float*)d_in[11];
    const float* cf2b = (const float*)d_in[12];
    a.intw = (const float*)d_in[13];
    const float* intb = (const float*)d_in[14];
    a.ow1  = (const float*)d_in[15];
    const float* ob1  = (const float*)d_in[16];
    const float* ow2  = (const float*)d_in[17];
    const float* ob2  = (const float*)d_in[18];
    a.dome = (const float*)d_in[19];
    a.fw1  = (const float*)d_in[20];
    a.fb1  = (const float*)d_in[21];
    a.fw2  = (const float*)d_in[22];
    a.fb2  = (const float*)d_in[23];
    a.bw   = (const float*)d_in[26];
    a.bb   = (const float*)d_in[27];

    char* ws = (char*)d_ws;
    a.epack   = (uint2*)(ws + 0);               // 2 MB
    uint* tab2= (uint*)(ws + 2*MB);             // 3 MB (interleaved pairs)
    a.h       = (float*)(ws + 5*MB);            // 4 MB
    a.xA      = (uint*)(ws + 9*MB);             // 2 MB
    uint* xB  = (uint*)(ws + 11*MB);            // 2 MB
    uint* agg = (uint*)(ws + 13*MB);            // 2 MB
    a.gbias   = (float*)(ws + 15*MB);           // 128 B
    a.wpack   = (uint*)(ws + 15*MB + 4096);     // 901 KB
    a.out = (float*)d_out;
    a.out_size = out_size;

    k_setup<<<512, 256, 0, stream>>>(a);
    k_table<<<192, 256, 0, stream>>>(a.wpack, mb1, mb2, tab2);

    const uint* xr = a.xA;
    uint* xw = xB;
    for (int l = 0; l < NLAYER; ++l) {
        k_gather<<<N_ATOMS/4, 256, 0, stream>>>(xr, tab2 + l*GTAB*128, a.epack, agg);
        const uint* w2p = a.wpack + (6 + l) * 8192;
        const uint* w3p = a.wpack + (12 + l) * 8192;
        if (l < NLAYER - 1) {
            k_gemmL<false><<<512, 256, 0, stream>>>(
                a.h, agg, xw, w2p, w3p, a.wpack + (l + 1) * 8192,
                cf2b + l*128, intb + l*128, ob1, ow2, ob2, a.gbias, a.out);
        } else {
            k_gemmL<true><<<512, 256, 0, stream>>>(
                a.h, agg, xw, w2p, w3p, a.wpack + OW1P_OFF,
                cf2b + l*128, intb + l*128, ob1, ow2, ob2, a.gbias, a.out);
        }
        const uint* tmp = xr; xr = xw; xw = (uint*)tmp;
    }
}

// Round 10
// 277.065 us; speedup vs baseline: 1.1614x; 1.1348x over previous
//
#include <hip/hip_runtime.h>
#include <math.h>

using uint = unsigned int;
typedef _Float16 h2    __attribute__((ext_vector_type(2)));
typedef _Float16 f16x8 __attribute__((ext_vector_type(8)));
typedef float    f32x4 __attribute__((ext_vector_type(4)));

#define N_ATOMS 8192
#define NEDGE   262144
#define KNBR    32
#define NGAUSS  50
#define NLAYER  6
#define NB      32
#define GTAB    1024
#define DMAX    8.6603f
#define FCUT    10.0f
#define MB      1048576

// MFMA LDS geometry (uints). Stride 76: 16B-aligned frags, 2-way banks (free).
#define LSTRIDE 76
#define S_WT    0               // 128*76 = 9728
#define S_AS    9728            // 16*76 = 1216
#define S_TS    10944           // 1216
#define GEMM_SMEM 12160         // 48.6 KB -> 3 blocks/CU

// table kernel LDS (uints)
#define T_W1    0               // 4096
#define T_W2    4096            // 8192
#define T_RBF   12288           // 1024
#define T_HID   13312           // 2048
#define TAB_SMEM 15360

// wpack layout (uints)
#define OW1P_OFF 147456         // 18 mats 128x128 (c,kp): cf1 x6 | cf2 x6 | int x6
#define M1_OFF   151552         // + ow1^T 64x64 (c,kp)
#define M2_OFF   176128         // + mlp_w1 f16 (kp,c) x6
#define WPACK_N  225280         // + mlp_w2 f16 (kp,c) x6

__device__ __forceinline__ float ssp(float x) {
    return fmaxf(x, 0.0f) + log1pf(expf(-fabsf(x))) - 0.69314718055994531f;
}
__device__ __forceinline__ uint pack2(float a, float b) {
    union { h2 h; uint u; } x;
    h2 v; v.x = (_Float16)a; v.y = (_Float16)b; x.h = v; return x.u;
}
__device__ __forceinline__ h2 u2h(uint u) {
    union { uint u; h2 h; } x; x.u = u; return x.h;
}
__device__ __forceinline__ uint h2u(h2 h) {
    union { h2 h; uint u; } x; x.h = h; return x.u;
}
__device__ __forceinline__ float fdot2f(h2 a, h2 b, float c) {
#if __has_builtin(__builtin_amdgcn_fdot2)
    return __builtin_amdgcn_fdot2(a, b, c, false);
#else
    return fmaf((float)a.y, (float)b.y, fmaf((float)a.x, (float)b.x, c));
#endif
}

// copy pre-packed W^T (c,kp) 64-stride -> LDS stride-76
__device__ __forceinline__ void stage_cp(uint* sm, const uint* __restrict__ src,
                                         int n16, int tid) {
    for (int i = tid; i < n16; i += 256) {
        uint4 v = ((const uint4*)src)[i];
        *(uint4*)&sm[(i >> 4) * LSTRIDE + (i & 15) * 4] = v;
    }
}

// MFMA: D[16 rows][NCT*16 cols] = As(16x128) @ WT^T, cols base nb
template<int NCT>
__device__ __forceinline__ void run_gemm(const uint* sm, int as_off, int lane,
                                         int nb, f32x4* acc) {
    int m = lane & 15, q = lane >> 4;
    #pragma unroll
    for (int ks = 0; ks < 4; ++ks) {
        f16x8 a = *(const f16x8*)&sm[as_off + m * LSTRIDE + q * 4 + ks * 16];
        #pragma unroll
        for (int ct = 0; ct < NCT; ++ct) {
            f16x8 b = *(const f16x8*)&sm[S_WT + (nb + ct * 16 + m) * LSTRIDE + q * 4 + ks * 16];
            acc[ct] = __builtin_amdgcn_mfma_f32_16x16x32_f16(a, b, acc[ct], 0, 0, 0);
        }
    }
}

struct SArgs {
    const float *pos; const int *z; const int *ei; const int *dom;
    const float *emb;
    const float *cf1; const float *cf2w; const float *intw; const float *ow1;
    const float *mw1; const float *mw2;
    const float *dome; const float *fw1; const float *fb1;
    const float *fw2; const float *fb2; const float *bw; const float *bb;
    uint2 *epack; float *h; uint *xA;
    float *gbias; uint *wpack; float *out; int out_size;
};

// ---------------------------------------------------------------------------
// setup: zero-out + wcvt + epack + embed + x0 GEMM + film (blocks 32..63)
__global__ void __launch_bounds__(256) k_setup(SArgs a) {
    __shared__ __align__(16) uint sm[S_AS + 1216];
    const int tid = threadIdx.x, bid = blockIdx.x;
    const int gidx = bid * 256 + tid, gsz = 512 * 256;
    const int lane = tid & 63, w = tid >> 6;
    const int m = lane & 15, q = lane >> 4;
    const int rowbase = bid * 16;

    for (int i = gidx; i < a.out_size; i += gsz) a.out[i] = 0.0f;

    // f16 weight pack
    for (int idx = gidx; idx < WPACK_N; idx += gsz) {
        if (idx < OW1P_OFF) {
            int mat = idx >> 13, e = idx & 8191;
            int kp = e >> 7, cc = e & 127;
            const float* src = (mat < 6) ? (a.cf1 + mat * 16384)
                            : (mat < 12) ? (a.cf2w + (mat - 6) * 16384)
                                         : (a.intw + (mat - 12) * 16384);
            a.wpack[mat * 8192 + cc * 64 + kp] =
                pack2(src[2 * kp * 128 + cc], src[(2 * kp + 1) * 128 + cc]);
        } else if (idx < M1_OFF) {
            int e = idx - OW1P_OFF;
            int kp = e >> 6, cc = e & 63;
            a.wpack[OW1P_OFF + cc * 64 + kp] =
                pack2(a.ow1[2 * kp * 64 + cc], a.ow1[(2 * kp + 1) * 64 + cc]);
        } else if (idx < M2_OFF) {
            int e = idx - M1_OFF;
            int l = e >> 12, r = e & 4095;
            int kp = r >> 7, cc = r & 127;
            int g0 = 2 * kp;
            float va = (g0 < NGAUSS)     ? a.mw1[l*NGAUSS*128 + g0*128 + cc]     : 0.f;
            float vb = (g0 + 1 < NGAUSS) ? a.mw1[l*NGAUSS*128 + (g0+1)*128 + cc] : 0.f;
            a.wpack[idx] = pack2(va, vb);
        } else {
            int e = idx - M2_OFF;
            int l = e >> 13, r = e & 8191;
            int kp = r >> 7, cc = r & 127;
            a.wpack[idx] = pack2(a.mw2[l*16384 + 2*kp*128 + cc],
                                 a.mw2[l*16384 + (2*kp+1)*128 + cc]);
        }
    }

    // epack: local 512 edges
    const float invdelta = (float)(GTAB - 1) / DMAX;
    #pragma unroll
    for (int t = 0; t < 2; ++t) {
        int e = rowbase * KNBR + t * 256 + tid;
        int s = a.ei[e], d = a.ei[NEDGE + e];
        float dx = a.pos[3*s] - a.pos[3*d];
        float dy = a.pos[3*s+1] - a.pos[3*d+1];
        float dz = a.pos[3*s+2] - a.pos[3*d+2];
        float dist = sqrtf(dx*dx + dy*dy + dz*dz);
        float u = dist * invdelta;
        int i0 = (int)u; i0 = (i0 < GTAB - 2) ? i0 : (GTAB - 2);
        float t2 = u - (float)i0;
        uint tb = pack2(t2, 0.0f) & 0xffffu;
        uint2 ep; ep.x = (uint)s; ep.y = (tb << 16) | (uint)i0;
        a.epack[e] = ep;
    }

    // embed -> h (f32) + As (f16)
    for (int i = tid; i < 1024; i += 256) {
        int r = i >> 6, f2 = i & 63;
        int zz = a.z[rowbase + r];
        float2 v = *(const float2*)&a.emb[zz * 128 + f2 * 2];
        *(float2*)&a.h[(rowbase + r) * 128 + f2 * 2] = v;
        sm[S_AS + r * LSTRIDE + f2] = pack2(v.x, v.y);
    }
    // WT <- cf1_0 (fp32 direct; wpack not yet visible within this kernel)
    for (int i = tid; i < 2048; i += 256) {
        int m4 = i >> 7, cc = i & 127;
        float v[8];
        #pragma unroll
        for (int j = 0; j < 8; ++j) v[j] = a.cf1[(8 * m4 + j) * 128 + cc];
        uint4 pk; pk.x = pack2(v[0], v[1]); pk.y = pack2(v[2], v[3]);
        pk.z = pack2(v[4], v[5]); pk.w = pack2(v[6], v[7]);
        *(uint4*)&sm[cc * LSTRIDE + m4 * 4] = pk;
    }
    __syncthreads();
    {   // x0 = h @ W1_0 -> xA
        f32x4 acc[2] = {{0,0,0,0},{0,0,0,0}};
        run_gemm<2>(sm, S_AS, lane, w * 32, acc);
        #pragma unroll
        for (int ct = 0; ct < 2; ++ct) {
            int n = w * 32 + ct * 16 + m;
            #pragma unroll
            for (int i = 0; i < 4; ++i) {
                float v = acc[ct][i];
                float u = __shfl_xor(v, 1, 64);
                if (!(lane & 1))
                    a.xA[(rowbase + q * 4 + i) * 64 + (n >> 1)] = pack2(v, u);
            }
        }
    }
    __syncthreads();
    if (bid >= 32 && bid < 64) {
        // FiLM beta sum (gamma path multiplies zeros), graph = bid-32
        int g = bid - 32;
        float* fs = (float*)sm;
        if (tid < 64) fs[tid] = a.dome[a.dom[g] * 64 + tid];
        __syncthreads();
        if (tid < 128) {
            float acc = a.fb1[tid];
            for (int i = 0; i < 64; ++i) acc = fmaf(fs[i], a.fw1[i*128 + tid], acc);
            fs[64 + tid] = fmaxf(acc, 0.0f);
        }
        __syncthreads();
        if (tid < 128) {
            float acc = a.fb2[tid];
            for (int i = 0; i < 128; ++i) acc = fmaf(fs[64+i], a.fw2[i*128 + tid], acc);
            fs[192 + tid] = acc;
        }
        __syncthreads();
        if (tid < 128) {
            float acc = a.bb[tid];
            for (int i = 0; i < 128; ++i) acc = fmaf(fs[192+i], a.bw[i*128 + tid], acc);
            #pragma unroll
            for (int off = 32; off > 0; off >>= 1) acc += __shfl_down(acc, off, 64);
            if ((tid & 63) == 0) fs[320 + (tid >> 6)] = acc;
        }
        __syncthreads();
        if (tid == 0) a.gbias[g] = fs[320] + fs[321];
    }
}

// ---------------------------------------------------------------------------
// filter tables from f16 wpack: 192 blocks = 6 layers x 32 chunks x 32 rows.
// Writes interleaved tab2: entry e holds rows {e, e+1} (16B per 2-feature group).
__global__ void __launch_bounds__(256) k_table(
    const uint* __restrict__ wpack, const float* __restrict__ mb1,
    const float* __restrict__ mb2, uint* __restrict__ tab2) {
    __shared__ __align__(16) uint sm[TAB_SMEM];
    const int tid = threadIdx.x;
    const int l = blockIdx.x >> 5;
    const int base = (blockIdx.x & 31) * 32;
    { const uint4* s4 = (const uint4*)(wpack + M1_OFF + l*4096);
      uint4* d4 = (uint4*)&sm[T_W1];
      for (int i = tid; i < 1024; i += 256) d4[i] = s4[i]; }
    { const uint4* s4 = (const uint4*)(wpack + M2_OFF + l*8192);
      uint4* d4 = (uint4*)&sm[T_W2];
      for (int i = tid; i < 2048; i += 256) d4[i] = s4[i]; }
    const float delta = DMAX / (float)(GTAB - 1);
    const float gstep = FCUT / (float)(NGAUSS - 1);
    const float coeff = -0.5f / (gstep * gstep);
    for (int i = tid; i < 1024; i += 256) {
        int r = i >> 5, kp = i & 31;
        float dv = (float)(base + r) * delta;
        int g0 = 2 * kp;
        float v0 = 0.f, v1 = 0.f;
        if (g0 < NGAUSS)     { float t = dv - (float)g0 * gstep;     v0 = expf(coeff*t*t); }
        if (g0 + 1 < NGAUSS) { float t = dv - (float)(g0+1) * gstep; v1 = expf(coeff*t*t); }
        sm[T_RBF + i] = pack2(v0, v1);
    }
    __syncthreads();
    int tx = tid & 31, ty = tid >> 5, c0 = tx * 4, tr0 = ty * 4;
    float acc[4][4];
    #pragma unroll
    for (int i = 0; i < 4; ++i) { acc[i][0]=0.f; acc[i][1]=0.f; acc[i][2]=0.f; acc[i][3]=0.f; }
    #pragma unroll
    for (int oct = 0; oct < 8; ++oct) {              // stage 1: K=50 (32 pairs)
        int kp0 = oct * 4;
        uint4 w_[4];
        #pragma unroll
        for (int p = 0; p < 4; ++p) w_[p] = *(const uint4*)&sm[T_W1 + (kp0+p)*128 + c0];
        #pragma unroll
        for (int i = 0; i < 4; ++i) {
            uint4 av = *(const uint4*)&sm[T_RBF + (tr0+i)*32 + kp0];
            uint aa[4] = {av.x, av.y, av.z, av.w};
            #pragma unroll
            for (int p = 0; p < 4; ++p) {
                h2 ap = u2h(aa[p]);
                acc[i][0] = fdot2f(ap, u2h(w_[p].x), acc[i][0]);
                acc[i][1] = fdot2f(ap, u2h(w_[p].y), acc[i][1]);
                acc[i][2] = fdot2f(ap, u2h(w_[p].z), acc[i][2]);
                acc[i][3] = fdot2f(ap, u2h(w_[p].w), acc[i][3]);
            }
        }
    }
    float4 b1v = *(const float4*)&mb1[l*128 + c0];
    #pragma unroll
    for (int i = 0; i < 4; ++i) {
        uint2 o;
        o.x = pack2(ssp(acc[i][0] + b1v.x), ssp(acc[i][1] + b1v.y));
        o.y = pack2(ssp(acc[i][2] + b1v.z), ssp(acc[i][3] + b1v.w));
        *(uint2*)&sm[T_HID + (tr0+i)*64 + (c0 >> 1)] = o;
    }
    __syncthreads();
    float acc2[4][4];
    #pragma unroll
    for (int i = 0; i < 4; ++i) { acc2[i][0]=0.f; acc2[i][1]=0.f; acc2[i][2]=0.f; acc2[i][3]=0.f; }
    #pragma unroll 4
    for (int oct = 0; oct < 16; ++oct) {             // stage 2: K=128
        int kp0 = oct * 4;
        uint4 w_[4];
        #pragma unroll
        for (int p = 0; p < 4; ++p) w_[p] = *(const uint4*)&sm[T_W2 + (kp0+p)*128 + c0];
        #pragma unroll
        for (int i = 0; i < 4; ++i) {
            uint4 av = *(const uint4*)&sm[T_HID + (tr0+i)*64 + kp0];
            uint aa[4] = {av.x, av.y, av.z, av.w};
            #pragma unroll
            for (int p = 0; p < 4; ++p) {
                h2 ap = u2h(aa[p]);
                acc2[i][0] = fdot2f(ap, u2h(w_[p].x), acc2[i][0]);
                acc2[i][1] = fdot2f(ap, u2h(w_[p].y), acc2[i][1]);
                acc2[i][2] = fdot2f(ap, u2h(w_[p].z), acc2[i][2]);
                acc2[i][3] = fdot2f(ap, u2h(w_[p].w), acc2[i][3]);
            }
        }
    }
    float4 b2v = *(const float4*)&mb2[l*128 + c0];
    #pragma unroll
    for (int i = 0; i < 4; ++i) {
        int row = base + tr0 + i;
        float dv = (float)row * delta;
        float Cd = 0.5f * (cosf(dv * 0.3141592653589793f) + 1.0f);
        uint2 o;
        o.x = pack2((acc2[i][0] + b2v.x)*Cd, (acc2[i][1] + b2v.y)*Cd);
        o.y = pack2((acc2[i][2] + b2v.z)*Cd, (acc2[i][3] + b2v.w)*Cd);
        *(uint2*)&tab2[(l*GTAB + row)*128 + tx*4] = o;          // own row, slots 0,1
        if (row > 0)
            *(uint2*)&tab2[(l*GTAB + row - 1)*128 + tx*4 + 2] = o;  // prev row, slots 2,3
    }
}

// ---------------------------------------------------------------------------
// edge gather, LDS-free. 1 wave per atom; 2 edges/iter (32 lanes each).
// tab2 dwordx4 gives both lerp endpoints in one load.
__global__ void __launch_bounds__(256) k_gather(
    const uint* __restrict__ xin, const uint* __restrict__ tab2l,
    const uint2* __restrict__ epack, uint* __restrict__ agg) {
    const int tid = threadIdx.x;
    const int lane = tid & 63;
    const int atom = blockIdx.x * 4 + (tid >> 6);
    const int side = lane >> 5, l5 = lane & 31;
    uint2 ep = epack[atom * KNBR + l5];
    h2 a0; a0.x = (_Float16)0; a0.y = (_Float16)0;
    h2 a1 = a0;
    #pragma unroll 4
    for (int k = 0; k < 16; ++k) {
        int e = 2 * k + side;
        uint s = __shfl(ep.x, e, 64);
        uint y = __shfl(ep.y, e, 64);
        int i0 = (int)(y & 0xffffu);
        uint th = y >> 16;
        h2 t2 = u2h(th | (th << 16));
        uint4 tv = *(const uint4*)&tab2l[i0 * 128 + l5 * 4];
        uint2 xv = *(const uint2*)&xin[s * 64 + l5 * 2];
        h2 w0 = u2h(tv.x) + t2 * (u2h(tv.z) - u2h(tv.x));
        h2 w1 = u2h(tv.y) + t2 * (u2h(tv.w) - u2h(tv.y));
        a0 = a0 + u2h(xv.x) * w0;
        a1 = a1 + u2h(xv.y) * w1;
    }
    uint u0 = h2u(a0), u1 = h2u(a1);
    uint p0 = __shfl_xor(u0, 32, 64), p1 = __shfl_xor(u1, 32, 64);
    if (side == 0) {
        h2 r0 = u2h(u0) + u2h(p0), r1 = u2h(u1) + u2h(p1);
        uint2 o; o.x = h2u(r0); o.y = h2u(r1);
        *(uint2*)&agg[atom * 64 + l5 * 2] = o;
    }
}

// ---------------------------------------------------------------------------
// GEMM part of a layer: Ts=ssp(agg@W2+b2); h+=Ts@W3+b3; x_next=h@W1n (or readout).
// Staging is direct global->LDS (stage_cp): full register budget for the GEMMs.
template<bool LAST>
__global__ void __launch_bounds__(256) k_gemmL(
    float* __restrict__ h, const uint* __restrict__ agg, uint* __restrict__ xout,
    const uint* __restrict__ w2p, const uint* __restrict__ w3p,
    const uint* __restrict__ w1np,
    const float* __restrict__ b2, const float* __restrict__ b3,
    const float* __restrict__ ob1, const float* __restrict__ ow2,
    const float* __restrict__ ob2, const float* __restrict__ gbias,
    float* __restrict__ out) {
    __shared__ __align__(16) uint sm[GEMM_SMEM];   // 48.6 KB -> 3 blocks/CU
    const int tid = threadIdx.x, bid = blockIdx.x;
    const int lane = tid & 63, w = tid >> 6;
    const int m = lane & 15, q = lane >> 4;
    const int rowbase = bid * 16;

    stage_cp(sm, w2p, 2048, tid);                         // W2 -> LDS
    {   uint4 v = ((const uint4*)(agg + rowbase * 64))[tid];
        *(uint4*)&sm[S_AS + (tid >> 4) * LSTRIDE + (tid & 15) * 4] = v; }
    __syncthreads();
    {   // Ts = ssp(As @ W2 + b2)
        f32x4 acc[2] = {{0,0,0,0},{0,0,0,0}};
        run_gemm<2>(sm, S_AS, lane, w * 32, acc);
        #pragma unroll
        for (int ct = 0; ct < 2; ++ct) {
            int n = w * 32 + ct * 16 + m;
            float bv = b2[n];
            #pragma unroll
            for (int i = 0; i < 4; ++i) {
                float v = ssp(acc[ct][i] + bv);
                float u = __shfl_xor(v, 1, 64);
                if (!(lane & 1))
                    sm[S_TS + (q * 4 + i) * LSTRIDE + (n >> 1)] = pack2(v, u);
            }
        }
    }
    __syncthreads();
    stage_cp(sm, w3p, 2048, tid);                         // W3 -> LDS
    __syncthreads();
    {   // h += Ts @ W3 + b3 ; As <- h_new
        f32x4 acc[2] = {{0,0,0,0},{0,0,0,0}};
        run_gemm<2>(sm, S_TS, lane, w * 32, acc);
        #pragma unroll
        for (int ct = 0; ct < 2; ++ct) {
            int n = w * 32 + ct * 16 + m;
            float bv = b3[n];
            #pragma unroll
            for (int i = 0; i < 4; ++i) {
                int r = rowbase + q * 4 + i;
                float hv = h[r * 128 + n] + acc[ct][i] + bv;
                h[r * 128 + n] = hv;
                float u = __shfl_xor(hv, 1, 64);
                if (!(lane & 1))
                    sm[S_AS + (q * 4 + i) * LSTRIDE + (n >> 1)] = pack2(hv, u);
            }
        }
    }
    __syncthreads();
    if (!LAST) {
        stage_cp(sm, w1np, 2048, tid);                    // W1_{l+1} -> LDS
        __syncthreads();
        f32x4 acc[2] = {{0,0,0,0},{0,0,0,0}};
        run_gemm<2>(sm, S_AS, lane, w * 32, acc);
        #pragma unroll
        for (int ct = 0; ct < 2; ++ct) {
            int n = w * 32 + ct * 16 + m;
            #pragma unroll
            for (int i = 0; i < 4; ++i) {
                float v = acc[ct][i];
                float u = __shfl_xor(v, 1, 64);
                if (!(lane & 1))
                    xout[(rowbase + q * 4 + i) * 64 + (n >> 1)] = pack2(v, u);
            }
        }
    } else {
        stage_cp(sm, w1np, 1024, tid);                    // ow1^T (64 cols)
        __syncthreads();
        f32x4 acc[1] = {{0,0,0,0}};
        run_gemm<1>(sm, S_AS, lane, w * 16, acc);
        int n = w * 16 + m;
        float b1v = ob1[n], w2v = ow2[n];
        float part = 0.f;
        #pragma unroll
        for (int i = 0; i < 4; ++i) part += ssp(acc[0][i] + b1v) * w2v;
        #pragma unroll
        for (int mm = 1; mm < 64; mm <<= 1) part += __shfl_xor(part, mm, 64);
        float* fs = (float*)&sm[S_TS];
        if (lane == 0) fs[w] = part;
        __syncthreads();
        if (tid == 0) {
            float bsum = fs[0] + fs[1] + fs[2] + fs[3] + 16.0f * ob2[0];
            float add = 32.0f * bsum;
            if ((bid & 15) == 0) {
                float sb = 0.f;
                for (int j = 0; j < NB; ++j) sb += gbias[j];
                add += sb;
            }
            atomicAdd(&out[bid >> 4], add);
        }
    }
}

// ---------------------------------------------------------------------------
extern "C" void kernel_launch(void* const* d_in, const int* in_sizes, int n_in,
                              void* d_out, int out_size, void* d_ws, size_t ws_size,
                              hipStream_t stream) {
    SArgs a;
    a.pos  = (const float*)d_in[0];
    a.z    = (const int*)d_in[1];
    a.ei   = (const int*)d_in[3];
    a.dom  = (const int*)d_in[4];
    a.emb  = (const float*)d_in[5];
    a.mw1  = (const float*)d_in[6];
    const float* mb1 = (const float*)d_in[7];
    a.mw2  = (const float*)d_in[8];
    const float* mb2 = (const float*)d_in[9];
    a.cf1  = (const float*)d_in[10];
    a.cf2w = (const float*)d_in[11];
    const float* cf2b = (const float*)d_in[12];
    a.intw = (const float*)d_in[13];
    const float* intb = (const float*)d_in[14];
    a.ow1  = (const float*)d_in[15];
    const float* ob1  = (const float*)d_in[16];
    const float* ow2  = (const float*)d_in[17];
    const float* ob2  = (const float*)d_in[18];
    a.dome = (const float*)d_in[19];
    a.fw1  = (const float*)d_in[20];
    a.fb1  = (const float*)d_in[21];
    a.fw2  = (const float*)d_in[22];
    a.fb2  = (const float*)d_in[23];
    a.bw   = (const float*)d_in[26];
    a.bb   = (const float*)d_in[27];

    char* ws = (char*)d_ws;
    a.epack   = (uint2*)(ws + 0);               // 2 MB
    uint* tab2= (uint*)(ws + 2*MB);             // 3 MB (interleaved pairs)
    a.h       = (float*)(ws + 5*MB);            // 4 MB
    a.xA      = (uint*)(ws + 9*MB);             // 2 MB
    uint* xB  = (uint*)(ws + 11*MB);            // 2 MB
    uint* agg = (uint*)(ws + 13*MB);            // 2 MB
    a.gbias   = (float*)(ws + 15*MB);           // 128 B
    a.wpack   = (uint*)(ws + 15*MB + 4096);     // 901 KB
    a.out = (float*)d_out;
    a.out_size = out_size;

    k_setup<<<512, 256, 0, stream>>>(a);
    k_table<<<192, 256, 0, stream>>>(a.wpack, mb1, mb2, tab2);

    const uint* xr = a.xA;
    uint* xw = xB;
    for (int l = 0; l < NLAYER; ++l) {
        k_gather<<<N_ATOMS/4, 256, 0, stream>>>(xr, tab2 + l*GTAB*128, a.epack, agg);
        const uint* w2p = a.wpack + (6 + l) * 8192;
        const uint* w3p = a.wpack + (12 + l) * 8192;
        if (l < NLAYER - 1) {
            k_gemmL<false><<<512, 256, 0, stream>>>(
                a.h, agg, xw, w2p, w3p, a.wpack + (l + 1) * 8192,
                cf2b + l*128, intb + l*128, ob1, ow2, ob2, a.gbias, a.out);
        } else {
            k_gemmL<true><<<512, 256, 0, stream>>>(
                a.h, agg, xw, w2p, w3p, a.wpack + OW1P_OFF,
                cf2b + l*128, intb + l*128, ob1, ow2, ob2, a.gbias, a.out);
        }
        const uint* tmp = xr; xr = xw; xw = (uint*)tmp;
    }
}

// Round 11
// 268.869 us; speedup vs baseline: 1.1968x; 1.0305x over previous
//
#include <hip/hip_runtime.h>
#include <math.h>

using uint = unsigned int;
typedef _Float16 h2    __attribute__((ext_vector_type(2)));
typedef _Float16 f16x8 __attribute__((ext_vector_type(8)));
typedef float    f32x4 __attribute__((ext_vector_type(4)));

#define N_ATOMS 8192
#define NEDGE   262144
#define KNBR    32
#define NGAUSS  50
#define NLAYER  6
#define NB      32
#define GTAB    1024
#define DMAX    8.6603f
#define FCUT    10.0f
#define MB      1048576

// MFMA LDS geometry (uints). Stride 76: 16B-aligned frags, 2-way banks (free).
#define LSTRIDE 76
#define S_WT    0               // 128*76 = 9728
#define S_AS    9728            // 16*76 = 1216
#define S_TS    10944           // 1216
#define GEMM_SMEM 12160         // 48.6 KB -> 3 blocks/CU

// table kernel LDS (uints)
#define T_W1    0               // 4096
#define T_W2    4096            // 8192
#define T_RBF   12288           // 1024
#define T_HID   13312           // 2048
#define TAB_SMEM 15360

// wpack layout (uints)
#define OW1P_OFF 147456         // 18 mats 128x128 (c,kp): cf1 x6 | cf2 x6 | int x6
#define M1_OFF   151552         // + ow1^T 64x64 (c,kp)
#define M2_OFF   176128         // + mlp_w1 f16 (kp,c) x6
#define WPACK_N  225280         // + mlp_w2 f16 (kp,c) x6

__device__ __forceinline__ float ssp(float x) {
    return fmaxf(x, 0.0f) + log1pf(expf(-fabsf(x))) - 0.69314718055994531f;
}
__device__ __forceinline__ uint pack2(float a, float b) {
    union { h2 h; uint u; } x;
    h2 v; v.x = (_Float16)a; v.y = (_Float16)b; x.h = v; return x.u;
}
__device__ __forceinline__ h2 u2h(uint u) {
    union { uint u; h2 h; } x; x.u = u; return x.h;
}
__device__ __forceinline__ uint h2u(h2 h) {
    union { h2 h; uint u; } x; x.h = h; return x.u;
}
__device__ __forceinline__ float fdot2f(h2 a, h2 b, float c) {
#if __has_builtin(__builtin_amdgcn_fdot2)
    return __builtin_amdgcn_fdot2(a, b, c, false);
#else
    return fmaf((float)a.y, (float)b.y, fmaf((float)a.x, (float)b.x, c));
#endif
}

// copy pre-packed W^T (c,kp) 64-stride -> LDS stride-76
__device__ __forceinline__ void stage_cp(uint* sm, const uint* __restrict__ src,
                                         int n16, int tid) {
    for (int i = tid; i < n16; i += 256) {
        uint4 v = ((const uint4*)src)[i];
        *(uint4*)&sm[(i >> 4) * LSTRIDE + (i & 15) * 4] = v;
    }
}

// MFMA: D[16 rows][NCT*16 cols] = As(16x128) @ WT^T, cols base nb
template<int NCT>
__device__ __forceinline__ void run_gemm(const uint* sm, int as_off, int lane,
                                         int nb, f32x4* acc) {
    int m = lane & 15, q = lane >> 4;
    #pragma unroll
    for (int ks = 0; ks < 4; ++ks) {
        f16x8 a = *(const f16x8*)&sm[as_off + m * LSTRIDE + q * 4 + ks * 16];
        #pragma unroll
        for (int ct = 0; ct < NCT; ++ct) {
            f16x8 b = *(const f16x8*)&sm[S_WT + (nb + ct * 16 + m) * LSTRIDE + q * 4 + ks * 16];
            acc[ct] = __builtin_amdgcn_mfma_f32_16x16x32_f16(a, b, acc[ct], 0, 0, 0);
        }
    }
}

struct SArgs {
    const float *pos; const int *z; const int *ei; const int *dom;
    const float *emb;
    const float *cf1; const float *cf2w; const float *intw; const float *ow1;
    const float *mw1; const float *mw2;
    const float *dome; const float *fw1; const float *fb1;
    const float *fw2; const float *fb2; const float *bw; const float *bb;
    uint2 *epack; float *h; uint *xA;
    float *gbias; uint *wpack; float *out; int out_size;
};

// ---------------------------------------------------------------------------
// setup: zero-out + wcvt + epack + embed + x0 GEMM + film (blocks 32..63)
__global__ void __launch_bounds__(256) k_setup(SArgs a) {
    __shared__ __align__(16) uint sm[S_AS + 1216];
    const int tid = threadIdx.x, bid = blockIdx.x;
    const int gidx = bid * 256 + tid, gsz = 512 * 256;
    const int lane = tid & 63, w = tid >> 6;
    const int m = lane & 15, q = lane >> 4;
    const int rowbase = bid * 16;

    for (int i = gidx; i < a.out_size; i += gsz) a.out[i] = 0.0f;

    // f16 weight pack
    for (int idx = gidx; idx < WPACK_N; idx += gsz) {
        if (idx < OW1P_OFF) {
            int mat = idx >> 13, e = idx & 8191;
            int kp = e >> 7, cc = e & 127;
            const float* src = (mat < 6) ? (a.cf1 + mat * 16384)
                            : (mat < 12) ? (a.cf2w + (mat - 6) * 16384)
                                         : (a.intw + (mat - 12) * 16384);
            a.wpack[mat * 8192 + cc * 64 + kp] =
                pack2(src[2 * kp * 128 + cc], src[(2 * kp + 1) * 128 + cc]);
        } else if (idx < M1_OFF) {
            int e = idx - OW1P_OFF;
            int kp = e >> 6, cc = e & 63;
            a.wpack[OW1P_OFF + cc * 64 + kp] =
                pack2(a.ow1[2 * kp * 64 + cc], a.ow1[(2 * kp + 1) * 64 + cc]);
        } else if (idx < M2_OFF) {
            int e = idx - M1_OFF;
            int l = e >> 12, r = e & 4095;
            int kp = r >> 7, cc = r & 127;
            int g0 = 2 * kp;
            float va = (g0 < NGAUSS)     ? a.mw1[l*NGAUSS*128 + g0*128 + cc]     : 0.f;
            float vb = (g0 + 1 < NGAUSS) ? a.mw1[l*NGAUSS*128 + (g0+1)*128 + cc] : 0.f;
            a.wpack[idx] = pack2(va, vb);
        } else {
            int e = idx - M2_OFF;
            int l = e >> 13, r = e & 8191;
            int kp = r >> 7, cc = r & 127;
            a.wpack[idx] = pack2(a.mw2[l*16384 + 2*kp*128 + cc],
                                 a.mw2[l*16384 + (2*kp+1)*128 + cc]);
        }
    }

    // epack: local 512 edges
    const float invdelta = (float)(GTAB - 1) / DMAX;
    #pragma unroll
    for (int t = 0; t < 2; ++t) {
        int e = rowbase * KNBR + t * 256 + tid;
        int s = a.ei[e], d = a.ei[NEDGE + e];
        float dx = a.pos[3*s] - a.pos[3*d];
        float dy = a.pos[3*s+1] - a.pos[3*d+1];
        float dz = a.pos[3*s+2] - a.pos[3*d+2];
        float dist = sqrtf(dx*dx + dy*dy + dz*dz);
        float u = dist * invdelta;
        int i0 = (int)u; i0 = (i0 < GTAB - 2) ? i0 : (GTAB - 2);
        float t2 = u - (float)i0;
        uint tb = pack2(t2, 0.0f) & 0xffffu;
        uint2 ep; ep.x = (uint)s; ep.y = (tb << 16) | (uint)i0;
        a.epack[e] = ep;
    }

    // embed -> h (f32) + As (f16)
    for (int i = tid; i < 1024; i += 256) {
        int r = i >> 6, f2 = i & 63;
        int zz = a.z[rowbase + r];
        float2 v = *(const float2*)&a.emb[zz * 128 + f2 * 2];
        *(float2*)&a.h[(rowbase + r) * 128 + f2 * 2] = v;
        sm[S_AS + r * LSTRIDE + f2] = pack2(v.x, v.y);
    }
    // WT <- cf1_0 (fp32 direct; wpack not yet visible within this kernel)
    for (int i = tid; i < 2048; i += 256) {
        int m4 = i >> 7, cc = i & 127;
        float v[8];
        #pragma unroll
        for (int j = 0; j < 8; ++j) v[j] = a.cf1[(8 * m4 + j) * 128 + cc];
        uint4 pk; pk.x = pack2(v[0], v[1]); pk.y = pack2(v[2], v[3]);
        pk.z = pack2(v[4], v[5]); pk.w = pack2(v[6], v[7]);
        *(uint4*)&sm[cc * LSTRIDE + m4 * 4] = pk;
    }
    __syncthreads();
    {   // x0 = h @ W1_0 -> xA
        f32x4 acc[2] = {{0,0,0,0},{0,0,0,0}};
        run_gemm<2>(sm, S_AS, lane, w * 32, acc);
        #pragma unroll
        for (int ct = 0; ct < 2; ++ct) {
            int n = w * 32 + ct * 16 + m;
            #pragma unroll
            for (int i = 0; i < 4; ++i) {
                float v = acc[ct][i];
                float u = __shfl_xor(v, 1, 64);
                if (!(lane & 1))
                    a.xA[(rowbase + q * 4 + i) * 64 + (n >> 1)] = pack2(v, u);
            }
        }
    }
    __syncthreads();
    if (bid >= 32 && bid < 64) {
        // FiLM beta sum (gamma path multiplies zeros), graph = bid-32
        int g = bid - 32;
        float* fs = (float*)sm;
        if (tid < 64) fs[tid] = a.dome[a.dom[g] * 64 + tid];
        __syncthreads();
        if (tid < 128) {
            float acc = a.fb1[tid];
            for (int i = 0; i < 64; ++i) acc = fmaf(fs[i], a.fw1[i*128 + tid], acc);
            fs[64 + tid] = fmaxf(acc, 0.0f);
        }
        __syncthreads();
        if (tid < 128) {
            float acc = a.fb2[tid];
            for (int i = 0; i < 128; ++i) acc = fmaf(fs[64+i], a.fw2[i*128 + tid], acc);
            fs[192 + tid] = acc;
        }
        __syncthreads();
        if (tid < 128) {
            float acc = a.bb[tid];
            for (int i = 0; i < 128; ++i) acc = fmaf(fs[192+i], a.bw[i*128 + tid], acc);
            #pragma unroll
            for (int off = 32; off > 0; off >>= 1) acc += __shfl_down(acc, off, 64);
            if ((tid & 63) == 0) fs[320 + (tid >> 6)] = acc;
        }
        __syncthreads();
        if (tid == 0) a.gbias[g] = fs[320] + fs[321];
    }
}

// ---------------------------------------------------------------------------
// filter tables from f16 wpack: 192 blocks = 6 layers x 32 chunks x 32 rows.
// Writes interleaved tab2: entry e holds rows {e, e+1} (16B per 2-feature group).
__global__ void __launch_bounds__(256) k_table(
    const uint* __restrict__ wpack, const float* __restrict__ mb1,
    const float* __restrict__ mb2, uint* __restrict__ tab2) {
    __shared__ __align__(16) uint sm[TAB_SMEM];
    const int tid = threadIdx.x;
    const int l = blockIdx.x >> 5;
    const int base = (blockIdx.x & 31) * 32;
    { const uint4* s4 = (const uint4*)(wpack + M1_OFF + l*4096);
      uint4* d4 = (uint4*)&sm[T_W1];
      for (int i = tid; i < 1024; i += 256) d4[i] = s4[i]; }
    { const uint4* s4 = (const uint4*)(wpack + M2_OFF + l*8192);
      uint4* d4 = (uint4*)&sm[T_W2];
      for (int i = tid; i < 2048; i += 256) d4[i] = s4[i]; }
    const float delta = DMAX / (float)(GTAB - 1);
    const float gstep = FCUT / (float)(NGAUSS - 1);
    const float coeff = -0.5f / (gstep * gstep);
    for (int i = tid; i < 1024; i += 256) {
        int r = i >> 5, kp = i & 31;
        float dv = (float)(base + r) * delta;
        int g0 = 2 * kp;
        float v0 = 0.f, v1 = 0.f;
        if (g0 < NGAUSS)     { float t = dv - (float)g0 * gstep;     v0 = expf(coeff*t*t); }
        if (g0 + 1 < NGAUSS) { float t = dv - (float)(g0+1) * gstep; v1 = expf(coeff*t*t); }
        sm[T_RBF + i] = pack2(v0, v1);
    }
    __syncthreads();
    int tx = tid & 31, ty = tid >> 5, c0 = tx * 4, tr0 = ty * 4;
    float acc[4][4];
    #pragma unroll
    for (int i = 0; i < 4; ++i) { acc[i][0]=0.f; acc[i][1]=0.f; acc[i][2]=0.f; acc[i][3]=0.f; }
    #pragma unroll
    for (int oct = 0; oct < 8; ++oct) {              // stage 1: K=50 (32 pairs)
        int kp0 = oct * 4;
        uint4 w_[4];
        #pragma unroll
        for (int p = 0; p < 4; ++p) w_[p] = *(const uint4*)&sm[T_W1 + (kp0+p)*128 + c0];
        #pragma unroll
        for (int i = 0; i < 4; ++i) {
            uint4 av = *(const uint4*)&sm[T_RBF + (tr0+i)*32 + kp0];
            uint aa[4] = {av.x, av.y, av.z, av.w};
            #pragma unroll
            for (int p = 0; p < 4; ++p) {
                h2 ap = u2h(aa[p]);
                acc[i][0] = fdot2f(ap, u2h(w_[p].x), acc[i][0]);
                acc[i][1] = fdot2f(ap, u2h(w_[p].y), acc[i][1]);
                acc[i][2] = fdot2f(ap, u2h(w_[p].z), acc[i][2]);
                acc[i][3] = fdot2f(ap, u2h(w_[p].w), acc[i][3]);
            }
        }
    }
    float4 b1v = *(const float4*)&mb1[l*128 + c0];
    #pragma unroll
    for (int i = 0; i < 4; ++i) {
        uint2 o;
        o.x = pack2(ssp(acc[i][0] + b1v.x), ssp(acc[i][1] + b1v.y));
        o.y = pack2(ssp(acc[i][2] + b1v.z), ssp(acc[i][3] + b1v.w));
        *(uint2*)&sm[T_HID + (tr0+i)*64 + (c0 >> 1)] = o;
    }
    __syncthreads();
    float acc2[4][4];
    #pragma unroll
    for (int i = 0; i < 4; ++i) { acc2[i][0]=0.f; acc2[i][1]=0.f; acc2[i][2]=0.f; acc2[i][3]=0.f; }
    #pragma unroll 4
    for (int oct = 0; oct < 16; ++oct) {             // stage 2: K=128
        int kp0 = oct * 4;
        uint4 w_[4];
        #pragma unroll
        for (int p = 0; p < 4; ++p) w_[p] = *(const uint4*)&sm[T_W2 + (kp0+p)*128 + c0];
        #pragma unroll
        for (int i = 0; i < 4; ++i) {
            uint4 av = *(const uint4*)&sm[T_HID + (tr0+i)*64 + kp0];
            uint aa[4] = {av.x, av.y, av.z, av.w};
            #pragma unroll
            for (int p = 0; p < 4; ++p) {
                h2 ap = u2h(aa[p]);
                acc2[i][0] = fdot2f(ap, u2h(w_[p].x), acc2[i][0]);
                acc2[i][1] = fdot2f(ap, u2h(w_[p].y), acc2[i][1]);
                acc2[i][2] = fdot2f(ap, u2h(w_[p].z), acc2[i][2]);
                acc2[i][3] = fdot2f(ap, u2h(w_[p].w), acc2[i][3]);
            }
        }
    }
    float4 b2v = *(const float4*)&mb2[l*128 + c0];
    #pragma unroll
    for (int i = 0; i < 4; ++i) {
        int row = base + tr0 + i;
        float dv = (float)row * delta;
        float Cd = 0.5f * (cosf(dv * 0.3141592653589793f) + 1.0f);
        uint2 o;
        o.x = pack2((acc2[i][0] + b2v.x)*Cd, (acc2[i][1] + b2v.y)*Cd);
        o.y = pack2((acc2[i][2] + b2v.z)*Cd, (acc2[i][3] + b2v.w)*Cd);
        *(uint2*)&tab2[(l*GTAB + row)*128 + tx*4] = o;          // own row, slots 0,1
        if (row > 0)
            *(uint2*)&tab2[(l*GTAB + row - 1)*128 + tx*4 + 2] = o;  // prev row, slots 2,3
    }
}

// ---------------------------------------------------------------------------
// Fused layer: LDS-free gather (overlapped with W2 staging) -> ssp(.@W2+b2)
// -> h += .@W3+b3 -> x_next = h@W1n (or readout). 512 blocks, 48.6 KB LDS.
template<bool LAST>
__global__ void __launch_bounds__(256) k_layer(
    float* __restrict__ h, const uint* __restrict__ xin, uint* __restrict__ xout,
    const uint* __restrict__ tab2l, const uint2* __restrict__ epack,
    const uint* __restrict__ w2p, const uint* __restrict__ w3p,
    const uint* __restrict__ w1np,
    const float* __restrict__ b2, const float* __restrict__ b3,
    const float* __restrict__ ob1, const float* __restrict__ ow2,
    const float* __restrict__ ob2, const float* __restrict__ gbias,
    float* __restrict__ out) {
    __shared__ __align__(16) uint sm[GEMM_SMEM];   // 48.6 KB -> 3 blocks/CU
    const int tid = threadIdx.x, bid = blockIdx.x;
    const int lane = tid & 63, w = tid >> 6;
    const int m = lane & 15, q = lane >> 4;
    const int rowbase = bid * 16;

    stage_cp(sm, w2p, 2048, tid);            // W2 loads fly under the gather
    {   // gather 16 atoms (4 per wave), 2 edges/iter per 32-lane side
        const int side = lane >> 5, l5 = lane & 31;
        #pragma unroll
        for (int p = 0; p < 4; ++p) {
            int al = p * 4 + w;
            uint2 ep = epack[(rowbase + al) * KNBR + l5];
            h2 a0; a0.x = (_Float16)0; a0.y = (_Float16)0;
            h2 a1 = a0;
            #pragma unroll 4
            for (int k = 0; k < 16; ++k) {
                int e = 2 * k + side;
                uint s = __shfl(ep.x, e, 64);
                uint y = __shfl(ep.y, e, 64);
                int i0 = (int)(y & 0xffffu);
                uint th = y >> 16;
                h2 t2 = u2h(th | (th << 16));
                uint4 tv = *(const uint4*)&tab2l[i0 * 128 + l5 * 4];
                uint2 xv = *(const uint2*)&xin[s * 64 + l5 * 2];
                h2 w0 = u2h(tv.x) + t2 * (u2h(tv.z) - u2h(tv.x));
                h2 w1 = u2h(tv.y) + t2 * (u2h(tv.w) - u2h(tv.y));
                a0 = a0 + u2h(xv.x) * w0;
                a1 = a1 + u2h(xv.y) * w1;
            }
            uint u0 = h2u(a0), u1 = h2u(a1);
            uint p0 = __shfl_xor(u0, 32, 64), p1 = __shfl_xor(u1, 32, 64);
            if (side == 0) {
                h2 r0 = u2h(u0) + u2h(p0), r1 = u2h(u1) + u2h(p1);
                uint2 o; o.x = h2u(r0); o.y = h2u(r1);
                *(uint2*)&sm[S_AS + al * LSTRIDE + l5 * 2] = o;
            }
        }
    }
    __syncthreads();
    {   // Ts = ssp(As @ W2 + b2)
        f32x4 acc[2] = {{0,0,0,0},{0,0,0,0}};
        run_gemm<2>(sm, S_AS, lane, w * 32, acc);
        #pragma unroll
        for (int ct = 0; ct < 2; ++ct) {
            int n = w * 32 + ct * 16 + m;
            float bv = b2[n];
            #pragma unroll
            for (int i = 0; i < 4; ++i) {
                float v = ssp(acc[ct][i] + bv);
                float u = __shfl_xor(v, 1, 64);
                if (!(lane & 1))
                    sm[S_TS + (q * 4 + i) * LSTRIDE + (n >> 1)] = pack2(v, u);
            }
        }
    }
    __syncthreads();
    stage_cp(sm, w3p, 2048, tid);                         // W3 -> LDS
    __syncthreads();
    {   // h += Ts @ W3 + b3 ; As <- h_new
        f32x4 acc[2] = {{0,0,0,0},{0,0,0,0}};
        run_gemm<2>(sm, S_TS, lane, w * 32, acc);
        #pragma unroll
        for (int ct = 0; ct < 2; ++ct) {
            int n = w * 32 + ct * 16 + m;
            float bv = b3[n];
            #pragma unroll
            for (int i = 0; i < 4; ++i) {
                int r = rowbase + q * 4 + i;
                float hv = h[r * 128 + n] + acc[ct][i] + bv;
                h[r * 128 + n] = hv;
                float u = __shfl_xor(hv, 1, 64);
                if (!(lane & 1))
                    sm[S_AS + (q * 4 + i) * LSTRIDE + (n >> 1)] = pack2(hv, u);
            }
        }
    }
    __syncthreads();
    if (!LAST) {
        stage_cp(sm, w1np, 2048, tid);                    // W1_{l+1} -> LDS
        __syncthreads();
        f32x4 acc[2] = {{0,0,0,0},{0,0,0,0}};
        run_gemm<2>(sm, S_AS, lane, w * 32, acc);
        #pragma unroll
        for (int ct = 0; ct < 2; ++ct) {
            int n = w * 32 + ct * 16 + m;
            #pragma unroll
            for (int i = 0; i < 4; ++i) {
                float v = acc[ct][i];
                float u = __shfl_xor(v, 1, 64);
                if (!(lane & 1))
                    xout[(rowbase + q * 4 + i) * 64 + (n >> 1)] = pack2(v, u);
            }
        }
    } else {
        stage_cp(sm, w1np, 1024, tid);                    // ow1^T (64 cols)
        __syncthreads();
        f32x4 acc[1] = {{0,0,0,0}};
        run_gemm<1>(sm, S_AS, lane, w * 16, acc);
        int n = w * 16 + m;
        float b1v = ob1[n], w2v = ow2[n];
        float part = 0.f;
        #pragma unroll
        for (int i = 0; i < 4; ++i) part += ssp(acc[0][i] + b1v) * w2v;
        #pragma unroll
        for (int mm = 1; mm < 64; mm <<= 1) part += __shfl_xor(part, mm, 64);
        float* fs = (float*)&sm[S_TS];
        if (lane == 0) fs[w] = part;
        __syncthreads();
        if (tid == 0) {
            float bsum = fs[0] + fs[1] + fs[2] + fs[3] + 16.0f * ob2[0];
            float add = 32.0f * bsum;
            if ((bid & 15) == 0) {
                float sb = 0.f;
                for (int j = 0; j < NB; ++j) sb += gbias[j];
                add += sb;
            }
            atomicAdd(&out[bid >> 4], add);
        }
    }
}

// ---------------------------------------------------------------------------
extern "C" void kernel_launch(void* const* d_in, const int* in_sizes, int n_in,
                              void* d_out, int out_size, void* d_ws, size_t ws_size,
                              hipStream_t stream) {
    SArgs a;
    a.pos  = (const float*)d_in[0];
    a.z    = (const int*)d_in[1];
    a.ei   = (const int*)d_in[3];
    a.dom  = (const int*)d_in[4];
    a.emb  = (const float*)d_in[5];
    a.mw1  = (const float*)d_in[6];
    const float* mb1 = (const float*)d_in[7];
    a.mw2  = (const float*)d_in[8];
    const float* mb2 = (const float*)d_in[9];
    a.cf1  = (const float*)d_in[10];
    a.cf2w = (const float*)d_in[11];
    const float* cf2b = (const float*)d_in[12];
    a.intw = (const float*)d_in[13];
    const float* intb = (const float*)d_in[14];
    a.ow1  = (const float*)d_in[15];
    const float* ob1  = (const float*)d_in[16];
    const float* ow2  = (const float*)d_in[17];
    const float* ob2  = (const float*)d_in[18];
    a.dome = (const float*)d_in[19];
    a.fw1  = (const float*)d_in[20];
    a.fb1  = (const float*)d_in[21];
    a.fw2  = (const float*)d_in[22];
    a.fb2  = (const float*)d_in[23];
    a.bw   = (const float*)d_in[26];
    a.bb   = (const float*)d_in[27];

    char* ws = (char*)d_ws;
    a.epack   = (uint2*)(ws + 0);               // 2 MB
    uint* tab2= (uint*)(ws + 2*MB);             // 3 MB (interleaved pairs)
    a.h       = (float*)(ws + 5*MB);            // 4 MB
    a.xA      = (uint*)(ws + 9*MB);             // 2 MB
    uint* xB  = (uint*)(ws + 11*MB);            // 2 MB
    a.gbias   = (float*)(ws + 15*MB);           // 128 B
    a.wpack   = (uint*)(ws + 15*MB + 4096);     // 901 KB
    a.out = (float*)d_out;
    a.out_size = out_size;

    k_setup<<<512, 256, 0, stream>>>(a);
    k_table<<<192, 256, 0, stream>>>(a.wpack, mb1, mb2, tab2);

    const uint* xr = a.xA;
    uint* xw = xB;
    for (int l = 0; l < NLAYER; ++l) {
        const uint* w2p = a.wpack + (6 + l) * 8192;
        const uint* w3p = a.wpack + (12 + l) * 8192;
        if (l < NLAYER - 1) {
            k_layer<false><<<512, 256, 0, stream>>>(
                a.h, xr, xw, tab2 + l*GTAB*128, a.epack, w2p, w3p,
                a.wpack + (l + 1) * 8192,
                cf2b + l*128, intb + l*128, ob1, ow2, ob2, a.gbias, a.out);
        } else {
            k_layer<true><<<512, 256, 0, stream>>>(
                a.h, xr, xw, tab2 + l*GTAB*128, a.epack, w2p, w3p,
                a.wpack + OW1P_OFF,
                cf2b + l*128, intb + l*128, ob1, ow2, ob2, a.gbias, a.out);
        }
        const uint* tmp = xr; xr = xw; xw = (uint*)tmp;
    }
}

// Round 12
// 266.952 us; speedup vs baseline: 1.2054x; 1.0072x over previous
//
#include <hip/hip_runtime.h>
#include <math.h>

using uint = unsigned int;
typedef _Float16 h2    __attribute__((ext_vector_type(2)));
typedef _Float16 f16x8 __attribute__((ext_vector_type(8)));
typedef float    f32x4 __attribute__((ext_vector_type(4)));

#define N_ATOMS 8192
#define NEDGE   262144
#define KNBR    32
#define NGAUSS  50
#define NLAYER  6
#define NB      32
#define GTAB    1024
#define DMAX    8.6603f
#define FCUT    10.0f
#define MB      1048576

// ---- k_setup legacy LDS geometry (stride 76) ----
#define LSTRIDE 76
#define S_WT    0               // 128*76 = 9728
#define S_AS    9728            // 16*76 = 1216

// ---- k_layer swizzled LDS geometry (stride 64, quad ^= row&15) ----
#define WA_OFF  0               // 8192 uints (32 KB)
#define WB_OFF  8192            // 8192
#define AS_OFF  16384           // 1024 (16 rows x 64)
#define TS_OFF  17408           // 1024
#define LAY_N   18432           // 72 KB -> 2 blocks/CU

// ---- k_table LDS ----
#define T_W1    0               // 4096
#define T_W2    4096            // 8192
#define T_RBF   12288           // 1024
#define T_HID   13312           // 2048
#define TAB_SMEM 15360

// wpack layout (uints)
#define OW1P_OFF 147456         // 18 mats 128x128 (c,kp): cf1 x6 | cf2 x6 | int x6
#define M1_OFF   151552         // + ow1^T 64x64 (c,kp)
#define M2_OFF   176128         // + mlp_w1 f16 (kp,c) x6
#define WPACK_N  225280         // + mlp_w2 f16 (kp,c) x6

__device__ __forceinline__ float ssp(float x) {
    return fmaxf(x, 0.0f) + log1pf(expf(-fabsf(x))) - 0.69314718055994531f;
}
__device__ __forceinline__ uint pack2(float a, float b) {
    union { h2 h; uint u; } x;
    h2 v; v.x = (_Float16)a; v.y = (_Float16)b; x.h = v; return x.u;
}
__device__ __forceinline__ h2 u2h(uint u) {
    union { uint u; h2 h; } x; x.u = u; return x.h;
}
__device__ __forceinline__ uint h2u(h2 h) {
    union { h2 h; uint u; } x; x.h = h; return x.u;
}
__device__ __forceinline__ float fdot2f(h2 a, h2 b, float c) {
#if __has_builtin(__builtin_amdgcn_fdot2)
    return __builtin_amdgcn_fdot2(a, b, c, false);
#else
    return fmaf((float)a.y, (float)b.y, fmaf((float)a.x, (float)b.x, c));
#endif
}

// ---- swizzled indexing: row-stride 64 uints, bank quad XORed with row&15 ----
__device__ __forceinline__ int swz(int row, int quad) {
    return row * 64 + ((quad ^ (row & 15)) << 2);
}
__device__ __forceinline__ int swzc(int row, int c) {   // c = uint column 0..63
    return row * 64 + (((c >> 2) ^ (row & 15)) << 2) + (c & 3);
}

// stage pre-packed W^T (c,kp) -> swizzled LDS region
__device__ __forceinline__ void stage_sw(uint* dst, const uint* __restrict__ src,
                                         int n16, int tid) {
    for (int i = tid; i < n16; i += 256) {
        uint4 v = ((const uint4*)src)[i];
        *(uint4*)&dst[swz(i >> 4, i & 15)] = v;
    }
}

// swizzled MFMA: D[16 rows][NCT*16 cols] = A(16x128) @ W^T, cols base nb
template<int NCT>
__device__ __forceinline__ void run_gemm_sw(const uint* smA, const uint* smW,
                                            int lane, int nb, f32x4* acc) {
    int m = lane & 15, q = lane >> 4;
    #pragma unroll
    for (int ks = 0; ks < 4; ++ks) {
        int cq = q + ks * 4;
        f16x8 a = *(const f16x8*)&smA[swz(m, cq)];
        #pragma unroll
        for (int ct = 0; ct < NCT; ++ct) {
            int n = nb + ct * 16 + m;
            f16x8 b = *(const f16x8*)&smW[swz(n, cq)];
            acc[ct] = __builtin_amdgcn_mfma_f32_16x16x32_f16(a, b, acc[ct], 0, 0, 0);
        }
    }
}

// legacy stride-76 gemm for k_setup
template<int NCT>
__device__ __forceinline__ void run_gemm(const uint* sm, int as_off, int lane,
                                         int nb, f32x4* acc) {
    int m = lane & 15, q = lane >> 4;
    #pragma unroll
    for (int ks = 0; ks < 4; ++ks) {
        f16x8 a = *(const f16x8*)&sm[as_off + m * LSTRIDE + q * 4 + ks * 16];
        #pragma unroll
        for (int ct = 0; ct < NCT; ++ct) {
            f16x8 b = *(const f16x8*)&sm[S_WT + (nb + ct * 16 + m) * LSTRIDE + q * 4 + ks * 16];
            acc[ct] = __builtin_amdgcn_mfma_f32_16x16x32_f16(a, b, acc[ct], 0, 0, 0);
        }
    }
}

struct SArgs {
    const float *pos; const int *z; const int *ei; const int *dom;
    const float *emb;
    const float *cf1; const float *cf2w; const float *intw; const float *ow1;
    const float *mw1; const float *mw2;
    const float *dome; const float *fw1; const float *fb1;
    const float *fw2; const float *fb2; const float *bw; const float *bb;
    uint2 *epack; float *h; uint *xA;
    float *gbias; uint *wpack; float *out; int out_size;
};

// ---------------------------------------------------------------------------
// setup: zero-out + wcvt + epack + embed + x0 GEMM + film (blocks 32..63)
__global__ void __launch_bounds__(256) k_setup(SArgs a) {
    __shared__ __align__(16) uint sm[S_AS + 1216];
    const int tid = threadIdx.x, bid = blockIdx.x;
    const int gidx = bid * 256 + tid, gsz = 512 * 256;
    const int lane = tid & 63, w = tid >> 6;
    const int m = lane & 15, q = lane >> 4;
    const int rowbase = bid * 16;

    for (int i = gidx; i < a.out_size; i += gsz) a.out[i] = 0.0f;

    for (int idx = gidx; idx < WPACK_N; idx += gsz) {
        if (idx < OW1P_OFF) {
            int mat = idx >> 13, e = idx & 8191;
            int kp = e >> 7, cc = e & 127;
            const float* src = (mat < 6) ? (a.cf1 + mat * 16384)
                            : (mat < 12) ? (a.cf2w + (mat - 6) * 16384)
                                         : (a.intw + (mat - 12) * 16384);
            a.wpack[mat * 8192 + cc * 64 + kp] =
                pack2(src[2 * kp * 128 + cc], src[(2 * kp + 1) * 128 + cc]);
        } else if (idx < M1_OFF) {
            int e = idx - OW1P_OFF;
            int kp = e >> 6, cc = e & 63;
            a.wpack[OW1P_OFF + cc * 64 + kp] =
                pack2(a.ow1[2 * kp * 64 + cc], a.ow1[(2 * kp + 1) * 64 + cc]);
        } else if (idx < M2_OFF) {
            int e = idx - M1_OFF;
            int l = e >> 12, r = e & 4095;
            int kp = r >> 7, cc = r & 127;
            int g0 = 2 * kp;
            float va = (g0 < NGAUSS)     ? a.mw1[l*NGAUSS*128 + g0*128 + cc]     : 0.f;
            float vb = (g0 + 1 < NGAUSS) ? a.mw1[l*NGAUSS*128 + (g0+1)*128 + cc] : 0.f;
            a.wpack[idx] = pack2(va, vb);
        } else {
            int e = idx - M2_OFF;
            int l = e >> 13, r = e & 8191;
            int kp = r >> 7, cc = r & 127;
            a.wpack[idx] = pack2(a.mw2[l*16384 + 2*kp*128 + cc],
                                 a.mw2[l*16384 + (2*kp+1)*128 + cc]);
        }
    }

    const float invdelta = (float)(GTAB - 1) / DMAX;
    #pragma unroll
    for (int t = 0; t < 2; ++t) {
        int e = rowbase * KNBR + t * 256 + tid;
        int s = a.ei[e], d = a.ei[NEDGE + e];
        float dx = a.pos[3*s] - a.pos[3*d];
        float dy = a.pos[3*s+1] - a.pos[3*d+1];
        float dz = a.pos[3*s+2] - a.pos[3*d+2];
        float dist = sqrtf(dx*dx + dy*dy + dz*dz);
        float u = dist * invdelta;
        int i0 = (int)u; i0 = (i0 < GTAB - 2) ? i0 : (GTAB - 2);
        float t2 = u - (float)i0;
        uint tb = pack2(t2, 0.0f) & 0xffffu;
        uint2 ep; ep.x = (uint)s; ep.y = (tb << 16) | (uint)i0;
        a.epack[e] = ep;
    }

    for (int i = tid; i < 1024; i += 256) {
        int r = i >> 6, f2 = i & 63;
        int zz = a.z[rowbase + r];
        float2 v = *(const float2*)&a.emb[zz * 128 + f2 * 2];
        *(float2*)&a.h[(rowbase + r) * 128 + f2 * 2] = v;
        sm[S_AS + r * LSTRIDE + f2] = pack2(v.x, v.y);
    }
    for (int i = tid; i < 2048; i += 256) {
        int m4 = i >> 7, cc = i & 127;
        float v[8];
        #pragma unroll
        for (int j = 0; j < 8; ++j) v[j] = a.cf1[(8 * m4 + j) * 128 + cc];
        uint4 pk; pk.x = pack2(v[0], v[1]); pk.y = pack2(v[2], v[3]);
        pk.z = pack2(v[4], v[5]); pk.w = pack2(v[6], v[7]);
        *(uint4*)&sm[cc * LSTRIDE + m4 * 4] = pk;
    }
    __syncthreads();
    {   // x0 = h @ W1_0 -> xA
        f32x4 acc[2] = {{0,0,0,0},{0,0,0,0}};
        run_gemm<2>(sm, S_AS, lane, w * 32, acc);
        #pragma unroll
        for (int ct = 0; ct < 2; ++ct) {
            int n = w * 32 + ct * 16 + m;
            #pragma unroll
            for (int i = 0; i < 4; ++i) {
                float v = acc[ct][i];
                float u = __shfl_xor(v, 1, 64);
                if (!(lane & 1))
                    a.xA[(rowbase + q * 4 + i) * 64 + (n >> 1)] = pack2(v, u);
            }
        }
    }
    __syncthreads();
    if (bid >= 32 && bid < 64) {
        int g = bid - 32;
        float* fs = (float*)sm;
        if (tid < 64) fs[tid] = a.dome[a.dom[g] * 64 + tid];
        __syncthreads();
        if (tid < 128) {
            float acc = a.fb1[tid];
            for (int i = 0; i < 64; ++i) acc = fmaf(fs[i], a.fw1[i*128 + tid], acc);
            fs[64 + tid] = fmaxf(acc, 0.0f);
        }
        __syncthreads();
        if (tid < 128) {
            float acc = a.fb2[tid];
            for (int i = 0; i < 128; ++i) acc = fmaf(fs[64+i], a.fw2[i*128 + tid], acc);
            fs[192 + tid] = acc;
        }
        __syncthreads();
        if (tid < 128) {
            float acc = a.bb[tid];
            for (int i = 0; i < 128; ++i) acc = fmaf(fs[192+i], a.bw[i*128 + tid], acc);
            #pragma unroll
            for (int off = 32; off > 0; off >>= 1) acc += __shfl_down(acc, off, 64);
            if ((tid & 63) == 0) fs[320 + (tid >> 6)] = acc;
        }
        __syncthreads();
        if (tid == 0) a.gbias[g] = fs[320] + fs[321];
    }
}

// ---------------------------------------------------------------------------
// filter tables from f16 wpack -> interleaved tab2 (rows {e, e+1} per entry)
__global__ void __launch_bounds__(256) k_table(
    const uint* __restrict__ wpack, const float* __restrict__ mb1,
    const float* __restrict__ mb2, uint* __restrict__ tab2) {
    __shared__ __align__(16) uint sm[TAB_SMEM];
    const int tid = threadIdx.x;
    const int l = blockIdx.x >> 5;
    const int base = (blockIdx.x & 31) * 32;
    { const uint4* s4 = (const uint4*)(wpack + M1_OFF + l*4096);
      uint4* d4 = (uint4*)&sm[T_W1];
      for (int i = tid; i < 1024; i += 256) d4[i] = s4[i]; }
    { const uint4* s4 = (const uint4*)(wpack + M2_OFF + l*8192);
      uint4* d4 = (uint4*)&sm[T_W2];
      for (int i = tid; i < 2048; i += 256) d4[i] = s4[i]; }
    const float delta = DMAX / (float)(GTAB - 1);
    const float gstep = FCUT / (float)(NGAUSS - 1);
    const float coeff = -0.5f / (gstep * gstep);
    for (int i = tid; i < 1024; i += 256) {
        int r = i >> 5, kp = i & 31;
        float dv = (float)(base + r) * delta;
        int g0 = 2 * kp;
        float v0 = 0.f, v1 = 0.f;
        if (g0 < NGAUSS)     { float t = dv - (float)g0 * gstep;     v0 = expf(coeff*t*t); }
        if (g0 + 1 < NGAUSS) { float t = dv - (float)(g0+1) * gstep; v1 = expf(coeff*t*t); }
        sm[T_RBF + i] = pack2(v0, v1);
    }
    __syncthreads();
    int tx = tid & 31, ty = tid >> 5, c0 = tx * 4, tr0 = ty * 4;
    float acc[4][4];
    #pragma unroll
    for (int i = 0; i < 4; ++i) { acc[i][0]=0.f; acc[i][1]=0.f; acc[i][2]=0.f; acc[i][3]=0.f; }
    #pragma unroll
    for (int oct = 0; oct < 8; ++oct) {
        int kp0 = oct * 4;
        uint4 w_[4];
        #pragma unroll
        for (int p = 0; p < 4; ++p) w_[p] = *(const uint4*)&sm[T_W1 + (kp0+p)*128 + c0];
        #pragma unroll
        for (int i = 0; i < 4; ++i) {
            uint4 av = *(const uint4*)&sm[T_RBF + (tr0+i)*32 + kp0];
            uint aa[4] = {av.x, av.y, av.z, av.w};
            #pragma unroll
            for (int p = 0; p < 4; ++p) {
                h2 ap = u2h(aa[p]);
                acc[i][0] = fdot2f(ap, u2h(w_[p].x), acc[i][0]);
                acc[i][1] = fdot2f(ap, u2h(w_[p].y), acc[i][1]);
                acc[i][2] = fdot2f(ap, u2h(w_[p].z), acc[i][2]);
                acc[i][3] = fdot2f(ap, u2h(w_[p].w), acc[i][3]);
            }
        }
    }
    float4 b1v = *(const float4*)&mb1[l*128 + c0];
    #pragma unroll
    for (int i = 0; i < 4; ++i) {
        uint2 o;
        o.x = pack2(ssp(acc[i][0] + b1v.x), ssp(acc[i][1] + b1v.y));
        o.y = pack2(ssp(acc[i][2] + b1v.z), ssp(acc[i][3] + b1v.w));
        *(uint2*)&sm[T_HID + (tr0+i)*64 + (c0 >> 1)] = o;
    }
    __syncthreads();
    float acc2[4][4];
    #pragma unroll
    for (int i = 0; i < 4; ++i) { acc2[i][0]=0.f; acc2[i][1]=0.f; acc2[i][2]=0.f; acc2[i][3]=0.f; }
    #pragma unroll 4
    for (int oct = 0; oct < 16; ++oct) {
        int kp0 = oct * 4;
        uint4 w_[4];
        #pragma unroll
        for (int p = 0; p < 4; ++p) w_[p] = *(const uint4*)&sm[T_W2 + (kp0+p)*128 + c0];
        #pragma unroll
        for (int i = 0; i < 4; ++i) {
            uint4 av = *(const uint4*)&sm[T_HID + (tr0+i)*64 + kp0];
            uint aa[4] = {av.x, av.y, av.z, av.w};
            #pragma unroll
            for (int p = 0; p < 4; ++p) {
                h2 ap = u2h(aa[p]);
                acc2[i][0] = fdot2f(ap, u2h(w_[p].x), acc2[i][0]);
                acc2[i][1] = fdot2f(ap, u2h(w_[p].y), acc2[i][1]);
                acc2[i][2] = fdot2f(ap, u2h(w_[p].z), acc2[i][2]);
                acc2[i][3] = fdot2f(ap, u2h(w_[p].w), acc2[i][3]);
            }
        }
    }
    float4 b2v = *(const float4*)&mb2[l*128 + c0];
    #pragma unroll
    for (int i = 0; i < 4; ++i) {
        int row = base + tr0 + i;
        float dv = (float)row * delta;
        float Cd = 0.5f * (cosf(dv * 0.3141592653589793f) + 1.0f);
        uint2 o;
        o.x = pack2((acc2[i][0] + b2v.x)*Cd, (acc2[i][1] + b2v.y)*Cd);
        o.y = pack2((acc2[i][2] + b2v.z)*Cd, (acc2[i][3] + b2v.w)*Cd);
        *(uint2*)&tab2[(l*GTAB + row)*128 + tx*4] = o;
        if (row > 0)
            *(uint2*)&tab2[(l*GTAB + row - 1)*128 + tx*4 + 2] = o;
    }
}

// ---------------------------------------------------------------------------
// Pipelined fused layer (3 barriers, W staging always hidden):
//   [stage W2 || gather] -> s1 -> [stage W3 || gemm2] -> s2
//   -> [stage W1n || gemm3+h] -> s3 -> gemm1 (or readout)
template<bool LAST>
__global__ void __launch_bounds__(256) k_layer(
    float* __restrict__ h, const uint* __restrict__ xin, uint* __restrict__ xout,
    const uint* __restrict__ tab2l, const uint2* __restrict__ epack,
    const uint* __restrict__ w2p, const uint* __restrict__ w3p,
    const uint* __restrict__ w1np,
    const float* __restrict__ b2, const float* __restrict__ b3,
    const float* __restrict__ ob1, const float* __restrict__ ow2,
    const float* __restrict__ ob2, const float* __restrict__ gbias,
    float* __restrict__ out) {
    __shared__ __align__(16) uint sm[LAY_N];   // 72 KB -> 2 blocks/CU
    const int tid = threadIdx.x, bid = blockIdx.x;
    const int lane = tid & 63, w = tid >> 6;
    const int m = lane & 15, q = lane >> 4;
    const int rowbase = bid * 16;

    // small h prefetch (8 VGPRs; loads fly under everything)
    float hr[2][4];
    #pragma unroll
    for (int ct = 0; ct < 2; ++ct)
        #pragma unroll
        for (int i = 0; i < 4; ++i)
            hr[ct][i] = h[(rowbase + q * 4 + i) * 128 + w * 32 + ct * 16 + m];

    stage_sw(&sm[WA_OFF], w2p, 2048, tid);     // W2 loads fly under gather
    {   // gather 16 atoms (4/wave), 2 edges/iter per 32-lane side
        const int side = lane >> 5, l5 = lane & 31;
        #pragma unroll
        for (int p = 0; p < 4; ++p) {
            int al = p * 4 + w;
            uint2 ep = epack[(rowbase + al) * KNBR + l5];
            h2 a0; a0.x = (_Float16)0; a0.y = (_Float16)0;
            h2 a1 = a0;
            #pragma unroll 4
            for (int k = 0; k < 16; ++k) {
                int e = 2 * k + side;
                uint s = __shfl(ep.x, e, 64);
                uint y = __shfl(ep.y, e, 64);
                int i0 = (int)(y & 0xffffu);
                uint th = y >> 16;
                h2 t2 = u2h(th | (th << 16));
                uint4 tv = *(const uint4*)&tab2l[i0 * 128 + l5 * 4];
                uint2 xv = *(const uint2*)&xin[s * 64 + l5 * 2];
                h2 w0 = u2h(tv.x) + t2 * (u2h(tv.z) - u2h(tv.x));
                h2 w1 = u2h(tv.y) + t2 * (u2h(tv.w) - u2h(tv.y));
                a0 = a0 + u2h(xv.x) * w0;
                a1 = a1 + u2h(xv.y) * w1;
            }
            uint u0 = h2u(a0), u1 = h2u(a1);
            uint p0 = __shfl_xor(u0, 32, 64), p1 = __shfl_xor(u1, 32, 64);
            if (side == 0) {
                h2 r0 = u2h(u0) + u2h(p0), r1 = u2h(u1) + u2h(p1);
                uint2 o; o.x = h2u(r0); o.y = h2u(r1);
                *(uint2*)&sm[AS_OFF + swzc(al, l5 * 2)] = o;
            }
        }
    }
    __syncthreads();                                      // (1) As + W2 ready
    stage_sw(&sm[WB_OFF], w3p, 2048, tid);                // W3 under gemm2
    {   // Ts = ssp(As @ W2 + b2)
        f32x4 acc[2] = {{0,0,0,0},{0,0,0,0}};
        run_gemm_sw<2>(&sm[AS_OFF], &sm[WA_OFF], lane, w * 32, acc);
        #pragma unroll
        for (int ct = 0; ct < 2; ++ct) {
            int n = w * 32 + ct * 16 + m;
            float bv = b2[n];
            #pragma unroll
            for (int i = 0; i < 4; ++i) {
                float v = ssp(acc[ct][i] + bv);
                float u = __shfl_xor(v, 1, 64);
                if (!(lane & 1))
                    sm[TS_OFF + swzc(q * 4 + i, n >> 1)] = pack2(v, u);
            }
        }
    }
    __syncthreads();                                      // (2) Ts + W3 ready
    stage_sw(&sm[WA_OFF], w1np, LAST ? 1024 : 2048, tid); // W1n/ow1 under gemm3
    {   // h += Ts @ W3 + b3 ; As <- h_new (f16)
        f32x4 acc[2] = {{0,0,0,0},{0,0,0,0}};
        run_gemm_sw<2>(&sm[TS_OFF], &sm[WB_OFF], lane, w * 32, acc);
        #pragma unroll
        for (int ct = 0; ct < 2; ++ct) {
            int n = w * 32 + ct * 16 + m;
            float bv = b3[n];
            #pragma unroll
            for (int i = 0; i < 4; ++i) {
                int r = rowbase + q * 4 + i;
                float hv = hr[ct][i] + acc[ct][i] + bv;
                h[r * 128 + n] = hv;
                float u = __shfl_xor(hv, 1, 64);
                if (!(lane & 1))
                    sm[AS_OFF + swzc(q * 4 + i, n >> 1)] = pack2(hv, u);
            }
        }
    }
    __syncthreads();                                      // (3) As(h) + W1n ready
    if (!LAST) {
        f32x4 acc[2] = {{0,0,0,0},{0,0,0,0}};
        run_gemm_sw<2>(&sm[AS_OFF], &sm[WA_OFF], lane, w * 32, acc);
        #pragma unroll
        for (int ct = 0; ct < 2; ++ct) {
            int n = w * 32 + ct * 16 + m;
            #pragma unroll
            for (int i = 0; i < 4; ++i) {
                float v = acc[ct][i];
                float u = __shfl_xor(v, 1, 64);
                if (!(lane & 1))
                    xout[(rowbase + q * 4 + i) * 64 + (n >> 1)] = pack2(v, u);
            }
        }
    } else {
        f32x4 acc[1] = {{0,0,0,0}};
        run_gemm_sw<1>(&sm[AS_OFF], &sm[WA_OFF], lane, w * 16, acc);
        int n = w * 16 + m;
        float b1v = ob1[n], w2v = ow2[n];
        float part = 0.f;
        #pragma unroll
        for (int i = 0; i < 4; ++i) part += ssp(acc[0][i] + b1v) * w2v;
        #pragma unroll
        for (int mm = 1; mm < 64; mm <<= 1) part += __shfl_xor(part, mm, 64);
        float* fs = (float*)&sm[TS_OFF];
        if (lane == 0) fs[w] = part;
        __syncthreads();
        if (tid == 0) {
            float bsum = fs[0] + fs[1] + fs[2] + fs[3] + 16.0f * ob2[0];
            float add = 32.0f * bsum;
            if ((bid & 15) == 0) {
                float sb = 0.f;
                for (int j = 0; j < NB; ++j) sb += gbias[j];
                add += sb;
            }
            atomicAdd(&out[bid >> 4], add);
        }
    }
}

// ---------------------------------------------------------------------------
extern "C" void kernel_launch(void* const* d_in, const int* in_sizes, int n_in,
                              void* d_out, int out_size, void* d_ws, size_t ws_size,
                              hipStream_t stream) {
    SArgs a;
    a.pos  = (const float*)d_in[0];
    a.z    = (const int*)d_in[1];
    a.ei   = (const int*)d_in[3];
    a.dom  = (const int*)d_in[4];
    a.emb  = (const float*)d_in[5];
    a.mw1  = (const float*)d_in[6];
    const float* mb1 = (const float*)d_in[7];
    a.mw2  = (const float*)d_in[8];
    const float* mb2 = (const float*)d_in[9];
    a.cf1  = (const float*)d_in[10];
    a.cf2w = (const float*)d_in[11];
    const float* cf2b = (const float*)d_in[12];
    a.intw = (const float*)d_in[13];
    const float* intb = (const float*)d_in[14];
    a.ow1  = (const float*)d_in[15];
    const float* ob1  = (const float*)d_in[16];
    const float* ow2  = (const float*)d_in[17];
    const float* ob2  = (const float*)d_in[18];
    a.dome = (const float*)d_in[19];
    a.fw1  = (const float*)d_in[20];
    a.fb1  = (const float*)d_in[21];
    a.fw2  = (const float*)d_in[22];
    a.fb2  = (const float*)d_in[23];
    a.bw   = (const float*)d_in[26];
    a.bb   = (const float*)d_in[27];

    char* ws = (char*)d_ws;
    a.epack   = (uint2*)(ws + 0);               // 2 MB
    uint* tab2= (uint*)(ws + 2*MB);             // 3 MB (interleaved pairs)
    a.h       = (float*)(ws + 5*MB);            // 4 MB
    a.xA      = (uint*)(ws + 9*MB);             // 2 MB
    uint* xB  = (uint*)(ws + 11*MB);            // 2 MB
    a.gbias   = (float*)(ws + 15*MB);           // 128 B
    a.wpack   = (uint*)(ws + 15*MB + 4096);     // 901 KB
    a.out = (float*)d_out;
    a.out_size = out_size;

    k_setup<<<512, 256, 0, stream>>>(a);
    k_table<<<192, 256, 0, stream>>>(a.wpack, mb1, mb2, tab2);

    const uint* xr = a.xA;
    uint* xw = xB;
    for (int l = 0; l < NLAYER; ++l) {
        const uint* w2p = a.wpack + (6 + l) * 8192;
        const uint* w3p = a.wpack + (12 + l) * 8192;
        if (l < NLAYER - 1) {
            k_layer<false><<<512, 256, 0, stream>>>(
                a.h, xr, xw, tab2 + l*GTAB*128, a.epack, w2p, w3p,
                a.wpack + (l + 1) * 8192,
                cf2b + l*128, intb + l*128, ob1, ow2, ob2, a.gbias, a.out);
        } else {
            k_layer<true><<<512, 256, 0, stream>>>(
                a.h, xr, xw, tab2 + l*GTAB*128, a.epack, w2p, w3p,
                a.wpack + OW1P_OFF,
                cf2b + l*128, intb + l*128, ob1, ow2, ob2, a.gbias, a.out);
        }
        const uint* tmp = xr; xr = xw; xw = (uint*)tmp;
    }
}

// Round 13
// 255.753 us; speedup vs baseline: 1.2581x; 1.0438x over previous
//
#include <hip/hip_runtime.h>
#include <math.h>

using uint = unsigned int;
typedef _Float16 h2    __attribute__((ext_vector_type(2)));
typedef _Float16 f16x8 __attribute__((ext_vector_type(8)));
typedef float    f32x4 __attribute__((ext_vector_type(4)));

#define N_ATOMS 8192
#define NEDGE   262144
#define KNBR    32
#define NGAUSS  50
#define NLAYER  6
#define NB      32
#define GTAB    1024
#define DMAX    8.6603f
#define FCUT    10.0f
#define MB      1048576

// ---- k_setup legacy LDS geometry (stride 76) ----
#define LSTRIDE 76
#define S_WT    0               // 128*76 = 9728
#define S_AS    9728            // 16*76 = 1216

// ---- k_layer swizzled LDS geometry (stride 64, quad ^= row&15) ----
#define WA_OFF  0               // 8192 uints (32 KB)
#define WB_OFF  8192            // 8192
#define AS_OFF  16384           // 1024 (16 rows x 64)
#define TS_OFF  17408           // 1024
#define LAY_N   18432           // 72 KB -> 2 blocks/CU

// ---- k_table LDS ----
#define T_W1    0               // 4096
#define T_W2    4096            // 8192
#define T_RBF   12288           // 1024
#define T_HID   13312           // 2048
#define TAB_SMEM 15360

// wpack layout (uints)
#define OW1P_OFF 147456         // 18 mats 128x128 (c,kp): cf1 x6 | cf2 x6 | int x6
#define M1_OFF   151552         // + ow1^T 64x64 (c,kp)
#define M2_OFF   176128         // + mlp_w1 f16 (kp,c) x6
#define WPACK_N  225280         // + mlp_w2 f16 (kp,c) x6

__device__ __forceinline__ float ssp(float x) {
    return fmaxf(x, 0.0f) + log1pf(expf(-fabsf(x))) - 0.69314718055994531f;
}
__device__ __forceinline__ uint pack2(float a, float b) {
    union { h2 h; uint u; } x;
    h2 v; v.x = (_Float16)a; v.y = (_Float16)b; x.h = v; return x.u;
}
__device__ __forceinline__ h2 u2h(uint u) {
    union { uint u; h2 h; } x; x.u = u; return x.h;
}
__device__ __forceinline__ uint h2u(h2 h) {
    union { h2 h; uint u; } x; x.h = h; return x.u;
}
__device__ __forceinline__ float fdot2f(h2 a, h2 b, float c) {
#if __has_builtin(__builtin_amdgcn_fdot2)
    return __builtin_amdgcn_fdot2(a, b, c, false);
#else
    return fmaf((float)a.y, (float)b.y, fmaf((float)a.x, (float)b.x, c));
#endif
}

// ---- swizzled indexing: row-stride 64 uints, bank quad XORed with row&15 ----
__device__ __forceinline__ int swz(int row, int quad) {
    return row * 64 + ((quad ^ (row & 15)) << 2);
}
__device__ __forceinline__ int swzc(int row, int c) {   // c = uint column 0..63
    return row * 64 + (((c >> 2) ^ (row & 15)) << 2) + (c & 3);
}

// stage pre-packed W^T (c,kp) -> swizzled LDS region
__device__ __forceinline__ void stage_sw(uint* dst, const uint* __restrict__ src,
                                         int n16, int tid) {
    for (int i = tid; i < n16; i += 256) {
        uint4 v = ((const uint4*)src)[i];
        *(uint4*)&dst[swz(i >> 4, i & 15)] = v;
    }
}

// swizzled MFMA: D[16 rows][NCT*16 cols] = A(16x128) @ W^T, cols base nb
template<int NCT>
__device__ __forceinline__ void run_gemm_sw(const uint* smA, const uint* smW,
                                            int lane, int nb, f32x4* acc) {
    int m = lane & 15, q = lane >> 4;
    #pragma unroll
    for (int ks = 0; ks < 4; ++ks) {
        int cq = q + ks * 4;
        f16x8 a = *(const f16x8*)&smA[swz(m, cq)];
        #pragma unroll
        for (int ct = 0; ct < NCT; ++ct) {
            int n = nb + ct * 16 + m;
            f16x8 b = *(const f16x8*)&smW[swz(n, cq)];
            acc[ct] = __builtin_amdgcn_mfma_f32_16x16x32_f16(a, b, acc[ct], 0, 0, 0);
        }
    }
}

// legacy stride-76 gemm for k_setup
template<int NCT>
__device__ __forceinline__ void run_gemm(const uint* sm, int as_off, int lane,
                                         int nb, f32x4* acc) {
    int m = lane & 15, q = lane >> 4;
    #pragma unroll
    for (int ks = 0; ks < 4; ++ks) {
        f16x8 a = *(const f16x8*)&sm[as_off + m * LSTRIDE + q * 4 + ks * 16];
        #pragma unroll
        for (int ct = 0; ct < NCT; ++ct) {
            f16x8 b = *(const f16x8*)&sm[S_WT + (nb + ct * 16 + m) * LSTRIDE + q * 4 + ks * 16];
            acc[ct] = __builtin_amdgcn_mfma_f32_16x16x32_f16(a, b, acc[ct], 0, 0, 0);
        }
    }
}

struct SArgs {
    const float *pos; const int *z; const int *ei; const int *dom;
    const float *emb;
    const float *cf1; const float *cf2w; const float *intw; const float *ow1;
    const float *mw1; const float *mw2;
    const float *dome; const float *fw1; const float *fb1;
    const float *fw2; const float *fb2; const float *bw; const float *bb;
    uint2 *epack; float *h; uint *xA;
    float *gbias; uint *wpack; float *out; int out_size;
};

// ---------------------------------------------------------------------------
// setup: zero-out + wcvt + epack + embed + x0 GEMM + film (blocks 32..63)
__global__ void __launch_bounds__(256) k_setup(SArgs a) {
    __shared__ __align__(16) uint sm[S_AS + 1216];
    const int tid = threadIdx.x, bid = blockIdx.x;
    const int gidx = bid * 256 + tid, gsz = 512 * 256;
    const int lane = tid & 63, w = tid >> 6;
    const int m = lane & 15, q = lane >> 4;
    const int rowbase = bid * 16;

    for (int i = gidx; i < a.out_size; i += gsz) a.out[i] = 0.0f;

    for (int idx = gidx; idx < WPACK_N; idx += gsz) {
        if (idx < OW1P_OFF) {
            int mat = idx >> 13, e = idx & 8191;
            int kp = e >> 7, cc = e & 127;
            const float* src = (mat < 6) ? (a.cf1 + mat * 16384)
                            : (mat < 12) ? (a.cf2w + (mat - 6) * 16384)
                                         : (a.intw + (mat - 12) * 16384);
            a.wpack[mat * 8192 + cc * 64 + kp] =
                pack2(src[2 * kp * 128 + cc], src[(2 * kp + 1) * 128 + cc]);
        } else if (idx < M1_OFF) {
            int e = idx - OW1P_OFF;
            int kp = e >> 6, cc = e & 63;
            a.wpack[OW1P_OFF + cc * 64 + kp] =
                pack2(a.ow1[2 * kp * 64 + cc], a.ow1[(2 * kp + 1) * 64 + cc]);
        } else if (idx < M2_OFF) {
            int e = idx - M1_OFF;
            int l = e >> 12, r = e & 4095;
            int kp = r >> 7, cc = r & 127;
            int g0 = 2 * kp;
            float va = (g0 < NGAUSS)     ? a.mw1[l*NGAUSS*128 + g0*128 + cc]     : 0.f;
            float vb = (g0 + 1 < NGAUSS) ? a.mw1[l*NGAUSS*128 + (g0+1)*128 + cc] : 0.f;
            a.wpack[idx] = pack2(va, vb);
        } else {
            int e = idx - M2_OFF;
            int l = e >> 13, r = e & 8191;
            int kp = r >> 7, cc = r & 127;
            a.wpack[idx] = pack2(a.mw2[l*16384 + 2*kp*128 + cc],
                                 a.mw2[l*16384 + (2*kp+1)*128 + cc]);
        }
    }

    const float invdelta = (float)(GTAB - 1) / DMAX;
    #pragma unroll
    for (int t = 0; t < 2; ++t) {
        int e = rowbase * KNBR + t * 256 + tid;
        int s = a.ei[e], d = a.ei[NEDGE + e];
        float dx = a.pos[3*s] - a.pos[3*d];
        float dy = a.pos[3*s+1] - a.pos[3*d+1];
        float dz = a.pos[3*s+2] - a.pos[3*d+2];
        float dist = sqrtf(dx*dx + dy*dy + dz*dz);
        float u = dist * invdelta;
        int i0 = (int)u; i0 = (i0 < GTAB - 2) ? i0 : (GTAB - 2);
        float t2 = u - (float)i0;
        uint tb = pack2(t2, 0.0f) & 0xffffu;
        uint2 ep; ep.x = (uint)s; ep.y = (tb << 16) | (uint)i0;
        a.epack[e] = ep;
    }

    for (int i = tid; i < 1024; i += 256) {
        int r = i >> 6, f2 = i & 63;
        int zz = a.z[rowbase + r];
        float2 v = *(const float2*)&a.emb[zz * 128 + f2 * 2];
        *(float2*)&a.h[(rowbase + r) * 128 + f2 * 2] = v;
        sm[S_AS + r * LSTRIDE + f2] = pack2(v.x, v.y);
    }
    for (int i = tid; i < 2048; i += 256) {
        int m4 = i >> 7, cc = i & 127;
        float v[8];
        #pragma unroll
        for (int j = 0; j < 8; ++j) v[j] = a.cf1[(8 * m4 + j) * 128 + cc];
        uint4 pk; pk.x = pack2(v[0], v[1]); pk.y = pack2(v[2], v[3]);
        pk.z = pack2(v[4], v[5]); pk.w = pack2(v[6], v[7]);
        *(uint4*)&sm[cc * LSTRIDE + m4 * 4] = pk;
    }
    __syncthreads();
    {   // x0 = h @ W1_0 -> xA
        f32x4 acc[2] = {{0,0,0,0},{0,0,0,0}};
        run_gemm<2>(sm, S_AS, lane, w * 32, acc);
        #pragma unroll
        for (int ct = 0; ct < 2; ++ct) {
            int n = w * 32 + ct * 16 + m;
            #pragma unroll
            for (int i = 0; i < 4; ++i) {
                float v = acc[ct][i];
                float u = __shfl_xor(v, 1, 64);
                if (!(lane & 1))
                    a.xA[(rowbase + q * 4 + i) * 64 + (n >> 1)] = pack2(v, u);
            }
        }
    }
    __syncthreads();
    if (bid >= 32 && bid < 64) {
        int g = bid - 32;
        float* fs = (float*)sm;
        if (tid < 64) fs[tid] = a.dome[a.dom[g] * 64 + tid];
        __syncthreads();
        if (tid < 128) {
            float acc = a.fb1[tid];
            for (int i = 0; i < 64; ++i) acc = fmaf(fs[i], a.fw1[i*128 + tid], acc);
            fs[64 + tid] = fmaxf(acc, 0.0f);
        }
        __syncthreads();
        if (tid < 128) {
            float acc = a.fb2[tid];
            for (int i = 0; i < 128; ++i) acc = fmaf(fs[64+i], a.fw2[i*128 + tid], acc);
            fs[192 + tid] = acc;
        }
        __syncthreads();
        if (tid < 128) {
            float acc = a.bb[tid];
            for (int i = 0; i < 128; ++i) acc = fmaf(fs[192+i], a.bw[i*128 + tid], acc);
            #pragma unroll
            for (int off = 32; off > 0; off >>= 1) acc += __shfl_down(acc, off, 64);
            if ((tid & 63) == 0) fs[320 + (tid >> 6)] = acc;
        }
        __syncthreads();
        if (tid == 0) a.gbias[g] = fs[320] + fs[321];
    }
}

// ---------------------------------------------------------------------------
// filter tables from f16 wpack -> interleaved tab2 (rows {e, e+1} per entry)
__global__ void __launch_bounds__(256) k_table(
    const uint* __restrict__ wpack, const float* __restrict__ mb1,
    const float* __restrict__ mb2, uint* __restrict__ tab2) {
    __shared__ __align__(16) uint sm[TAB_SMEM];
    const int tid = threadIdx.x;
    const int l = blockIdx.x >> 5;
    const int base = (blockIdx.x & 31) * 32;
    { const uint4* s4 = (const uint4*)(wpack + M1_OFF + l*4096);
      uint4* d4 = (uint4*)&sm[T_W1];
      for (int i = tid; i < 1024; i += 256) d4[i] = s4[i]; }
    { const uint4* s4 = (const uint4*)(wpack + M2_OFF + l*8192);
      uint4* d4 = (uint4*)&sm[T_W2];
      for (int i = tid; i < 2048; i += 256) d4[i] = s4[i]; }
    const float delta = DMAX / (float)(GTAB - 1);
    const float gstep = FCUT / (float)(NGAUSS - 1);
    const float coeff = -0.5f / (gstep * gstep);
    for (int i = tid; i < 1024; i += 256) {
        int r = i >> 5, kp = i & 31;
        float dv = (float)(base + r) * delta;
        int g0 = 2 * kp;
        float v0 = 0.f, v1 = 0.f;
        if (g0 < NGAUSS)     { float t = dv - (float)g0 * gstep;     v0 = expf(coeff*t*t); }
        if (g0 + 1 < NGAUSS) { float t = dv - (float)(g0+1) * gstep; v1 = expf(coeff*t*t); }
        sm[T_RBF + i] = pack2(v0, v1);
    }
    __syncthreads();
    int tx = tid & 31, ty = tid >> 5, c0 = tx * 4, tr0 = ty * 4;
    float acc[4][4];
    #pragma unroll
    for (int i = 0; i < 4; ++i) { acc[i][0]=0.f; acc[i][1]=0.f; acc[i][2]=0.f; acc[i][3]=0.f; }
    #pragma unroll
    for (int oct = 0; oct < 8; ++oct) {
        int kp0 = oct * 4;
        uint4 w_[4];
        #pragma unroll
        for (int p = 0; p < 4; ++p) w_[p] = *(const uint4*)&sm[T_W1 + (kp0+p)*128 + c0];
        #pragma unroll
        for (int i = 0; i < 4; ++i) {
            uint4 av = *(const uint4*)&sm[T_RBF + (tr0+i)*32 + kp0];
            uint aa[4] = {av.x, av.y, av.z, av.w};
            #pragma unroll
            for (int p = 0; p < 4; ++p) {
                h2 ap = u2h(aa[p]);
                acc[i][0] = fdot2f(ap, u2h(w_[p].x), acc[i][0]);
                acc[i][1] = fdot2f(ap, u2h(w_[p].y), acc[i][1]);
                acc[i][2] = fdot2f(ap, u2h(w_[p].z), acc[i][2]);
                acc[i][3] = fdot2f(ap, u2h(w_[p].w), acc[i][3]);
            }
        }
    }
    float4 b1v = *(const float4*)&mb1[l*128 + c0];
    #pragma unroll
    for (int i = 0; i < 4; ++i) {
        uint2 o;
        o.x = pack2(ssp(acc[i][0] + b1v.x), ssp(acc[i][1] + b1v.y));
        o.y = pack2(ssp(acc[i][2] + b1v.z), ssp(acc[i][3] + b1v.w));
        *(uint2*)&sm[T_HID + (tr0+i)*64 + (c0 >> 1)] = o;
    }
    __syncthreads();
    float acc2[4][4];
    #pragma unroll
    for (int i = 0; i < 4; ++i) { acc2[i][0]=0.f; acc2[i][1]=0.f; acc2[i][2]=0.f; acc2[i][3]=0.f; }
    #pragma unroll 4
    for (int oct = 0; oct < 16; ++oct) {
        int kp0 = oct * 4;
        uint4 w_[4];
        #pragma unroll
        for (int p = 0; p < 4; ++p) w_[p] = *(const uint4*)&sm[T_W2 + (kp0+p)*128 + c0];
        #pragma unroll
        for (int i = 0; i < 4; ++i) {
            uint4 av = *(const uint4*)&sm[T_HID + (tr0+i)*64 + kp0];
            uint aa[4] = {av.x, av.y, av.z, av.w};
            #pragma unroll
            for (int p = 0; p < 4; ++p) {
                h2 ap = u2h(aa[p]);
                acc2[i][0] = fdot2f(ap, u2h(w_[p].x), acc2[i][0]);
                acc2[i][1] = fdot2f(ap, u2h(w_[p].y), acc2[i][1]);
                acc2[i][2] = fdot2f(ap, u2h(w_[p].z), acc2[i][2]);
                acc2[i][3] = fdot2f(ap, u2h(w_[p].w), acc2[i][3]);
            }
        }
    }
    float4 b2v = *(const float4*)&mb2[l*128 + c0];
    #pragma unroll
    for (int i = 0; i < 4; ++i) {
        int row = base + tr0 + i;
        float dv = (float)row * delta;
        float Cd = 0.5f * (cosf(dv * 0.3141592653589793f) + 1.0f);
        uint2 o;
        o.x = pack2((acc2[i][0] + b2v.x)*Cd, (acc2[i][1] + b2v.y)*Cd);
        o.y = pack2((acc2[i][2] + b2v.z)*Cd, (acc2[i][3] + b2v.w)*Cd);
        *(uint2*)&tab2[(l*GTAB + row)*128 + tx*4] = o;
        if (row > 0)
            *(uint2*)&tab2[(l*GTAB + row - 1)*128 + tx*4 + 2] = o;
    }
}

// ---------------------------------------------------------------------------
// Pipelined fused layer with XCD-aware graph placement:
//   XCD x (= bid&7, empirical MI355X round-robin) owns graphs 4x..4x+3, so the
//   per-XCD L2 working set (tab2_l 0.5MB + x 256KB + epack 256KB + h 512KB +
//   W 96KB ~= 1.6MB) fits in 4MB and x written at layer l is re-read at l+1
//   on the same XCD. Pure block->atom-range permutation; correctness-neutral.
template<bool LAST>
__global__ void __launch_bounds__(256) k_layer(
    float* __restrict__ h, const uint* __restrict__ xin, uint* __restrict__ xout,
    const uint* __restrict__ tab2l, const uint2* __restrict__ epack,
    const uint* __restrict__ w2p, const uint* __restrict__ w3p,
    const uint* __restrict__ w1np,
    const float* __restrict__ b2, const float* __restrict__ b3,
    const float* __restrict__ ob1, const float* __restrict__ ow2,
    const float* __restrict__ ob2, const float* __restrict__ gbias,
    float* __restrict__ out) {
    __shared__ __align__(16) uint sm[LAY_N];   // 72 KB -> 2 blocks/CU
    const int tid = threadIdx.x, bid = blockIdx.x;
    const int lane = tid & 63, w = tid >> 6;
    const int m = lane & 15, q = lane >> 4;
    // XCD-aware mapping: bid -> (graph, sub-block)
    const int xcd = bid & 7;
    const int j   = bid >> 3;                  // 0..63
    const int g   = xcd * 4 + (j >> 4);        // graph 0..31
    const int sub = j & 15;
    const int rowbase = g * 256 + sub * 16;

    // small h prefetch (8 VGPRs; loads fly under everything)
    float hr[2][4];
    #pragma unroll
    for (int ct = 0; ct < 2; ++ct)
        #pragma unroll
        for (int i = 0; i < 4; ++i)
            hr[ct][i] = h[(rowbase + q * 4 + i) * 128 + w * 32 + ct * 16 + m];

    stage_sw(&sm[WA_OFF], w2p, 2048, tid);     // W2 loads fly under gather
    {   // gather 16 atoms (4/wave), 2 edges/iter per 32-lane side
        const int side = lane >> 5, l5 = lane & 31;
        #pragma unroll
        for (int p = 0; p < 4; ++p) {
            int al = p * 4 + w;
            uint2 ep = epack[(rowbase + al) * KNBR + l5];
            h2 a0; a0.x = (_Float16)0; a0.y = (_Float16)0;
            h2 a1 = a0;
            #pragma unroll 4
            for (int k = 0; k < 16; ++k) {
                int e = 2 * k + side;
                uint s = __shfl(ep.x, e, 64);
                uint y = __shfl(ep.y, e, 64);
                int i0 = (int)(y & 0xffffu);
                uint th = y >> 16;
                h2 t2 = u2h(th | (th << 16));
                uint4 tv = *(const uint4*)&tab2l[i0 * 128 + l5 * 4];
                uint2 xv = *(const uint2*)&xin[s * 64 + l5 * 2];
                h2 w0 = u2h(tv.x) + t2 * (u2h(tv.z) - u2h(tv.x));
                h2 w1 = u2h(tv.y) + t2 * (u2h(tv.w) - u2h(tv.y));
                a0 = a0 + u2h(xv.x) * w0;
                a1 = a1 + u2h(xv.y) * w1;
            }
            uint u0 = h2u(a0), u1 = h2u(a1);
            uint p0 = __shfl_xor(u0, 32, 64), p1 = __shfl_xor(u1, 32, 64);
            if (side == 0) {
                h2 r0 = u2h(u0) + u2h(p0), r1 = u2h(u1) + u2h(p1);
                uint2 o; o.x = h2u(r0); o.y = h2u(r1);
                *(uint2*)&sm[AS_OFF + swzc(al, l5 * 2)] = o;
            }
        }
    }
    __syncthreads();                                      // (1) As + W2 ready
    stage_sw(&sm[WB_OFF], w3p, 2048, tid);                // W3 under gemm2
    {   // Ts = ssp(As @ W2 + b2)
        f32x4 acc[2] = {{0,0,0,0},{0,0,0,0}};
        run_gemm_sw<2>(&sm[AS_OFF], &sm[WA_OFF], lane, w * 32, acc);
        #pragma unroll
        for (int ct = 0; ct < 2; ++ct) {
            int n = w * 32 + ct * 16 + m;
            float bv = b2[n];
            #pragma unroll
            for (int i = 0; i < 4; ++i) {
                float v = ssp(acc[ct][i] + bv);
                float u = __shfl_xor(v, 1, 64);
                if (!(lane & 1))
                    sm[TS_OFF + swzc(q * 4 + i, n >> 1)] = pack2(v, u);
            }
        }
    }
    __syncthreads();                                      // (2) Ts + W3 ready
    stage_sw(&sm[WA_OFF], w1np, LAST ? 1024 : 2048, tid); // W1n/ow1 under gemm3
    {   // h += Ts @ W3 + b3 ; As <- h_new (f16)
        f32x4 acc[2] = {{0,0,0,0},{0,0,0,0}};
        run_gemm_sw<2>(&sm[TS_OFF], &sm[WB_OFF], lane, w * 32, acc);
        #pragma unroll
        for (int ct = 0; ct < 2; ++ct) {
            int n = w * 32 + ct * 16 + m;
            float bv = b3[n];
            #pragma unroll
            for (int i = 0; i < 4; ++i) {
                int r = rowbase + q * 4 + i;
                float hv = hr[ct][i] + acc[ct][i] + bv;
                h[r * 128 + n] = hv;
                float u = __shfl_xor(hv, 1, 64);
                if (!(lane & 1))
                    sm[AS_OFF + swzc(q * 4 + i, n >> 1)] = pack2(hv, u);
            }
        }
    }
    __syncthreads();                                      // (3) As(h) + W1n ready
    if (!LAST) {
        f32x4 acc[2] = {{0,0,0,0},{0,0,0,0}};
        run_gemm_sw<2>(&sm[AS_OFF], &sm[WA_OFF], lane, w * 32, acc);
        #pragma unroll
        for (int ct = 0; ct < 2; ++ct) {
            int n = w * 32 + ct * 16 + m;
            #pragma unroll
            for (int i = 0; i < 4; ++i) {
                float v = acc[ct][i];
                float u = __shfl_xor(v, 1, 64);
                if (!(lane & 1))
                    xout[(rowbase + q * 4 + i) * 64 + (n >> 1)] = pack2(v, u);
            }
        }
    } else {
        f32x4 acc[1] = {{0,0,0,0}};
        run_gemm_sw<1>(&sm[AS_OFF], &sm[WA_OFF], lane, w * 16, acc);
        int n = w * 16 + m;
        float b1v = ob1[n], w2v = ow2[n];
        float part = 0.f;
        #pragma unroll
        for (int i = 0; i < 4; ++i) part += ssp(acc[0][i] + b1v) * w2v;
        #pragma unroll
        for (int mm = 1; mm < 64; mm <<= 1) part += __shfl_xor(part, mm, 64);
        float* fs = (float*)&sm[TS_OFF];
        if (lane == 0) fs[w] = part;
        __syncthreads();
        if (tid == 0) {
            float bsum = fs[0] + fs[1] + fs[2] + fs[3] + 16.0f * ob2[0];
            float add = 32.0f * bsum;
            if (sub == 0) {
                float sb = 0.f;
                for (int jj = 0; jj < NB; ++jj) sb += gbias[jj];
                add += sb;
            }
            atomicAdd(&out[g], add);
        }
    }
}

// ---------------------------------------------------------------------------
extern "C" void kernel_launch(void* const* d_in, const int* in_sizes, int n_in,
                              void* d_out, int out_size, void* d_ws, size_t ws_size,
                              hipStream_t stream) {
    SArgs a;
    a.pos  = (const float*)d_in[0];
    a.z    = (const int*)d_in[1];
    a.ei   = (const int*)d_in[3];
    a.dom  = (const int*)d_in[4];
    a.emb  = (const float*)d_in[5];
    a.mw1  = (const float*)d_in[6];
    const float* mb1 = (const float*)d_in[7];
    a.mw2  = (const float*)d_in[8];
    const float* mb2 = (const float*)d_in[9];
    a.cf1  = (const float*)d_in[10];
    a.cf2w = (const float*)d_in[11];
    const float* cf2b = (const float*)d_in[12];
    a.intw = (const float*)d_in[13];
    const float* intb = (const float*)d_in[14];
    a.ow1  = (const float*)d_in[15];
    const float* ob1  = (const float*)d_in[16];
    const float* ow2  = (const float*)d_in[17];
    const float* ob2  = (const float*)d_in[18];
    a.dome = (const float*)d_in[19];
    a.fw1  = (const float*)d_in[20];
    a.fb1  = (const float*)d_in[21];
    a.fw2  = (const float*)d_in[22];
    a.fb2  = (const float*)d_in[23];
    a.bw   = (const float*)d_in[26];
    a.bb   = (const float*)d_in[27];

    char* ws = (char*)d_ws;
    a.epack   = (uint2*)(ws + 0);               // 2 MB
    uint* tab2= (uint*)(ws + 2*MB);             // 3 MB (interleaved pairs)
    a.h       = (float*)(ws + 5*MB);            // 4 MB
    a.xA      = (uint*)(ws + 9*MB);             // 2 MB
    uint* xB  = (uint*)(ws + 11*MB);            // 2 MB
    a.gbias   = (float*)(ws + 15*MB);           // 128 B
    a.wpack   = (uint*)(ws + 15*MB + 4096);     // 901 KB
    a.out = (float*)d_out;
    a.out_size = out_size;

    k_setup<<<512, 256, 0, stream>>>(a);
    k_table<<<192, 256, 0, stream>>>(a.wpack, mb1, mb2, tab2);

    const uint* xr = a.xA;
    uint* xw = xB;
    for (int l = 0; l < NLAYER; ++l) {
        const uint* w2p = a.wpack + (6 + l) * 8192;
        const uint* w3p = a.wpack + (12 + l) * 8192;
        if (l < NLAYER - 1) {
            k_layer<false><<<512, 256, 0, stream>>>(
                a.h, xr, xw, tab2 + l*GTAB*128, a.epack, w2p, w3p,
                a.wpack + (l + 1) * 8192,
                cf2b + l*128, intb + l*128, ob1, ow2, ob2, a.gbias, a.out);
        } else {
            k_layer<true><<<512, 256, 0, stream>>>(
                a.h, xr, xw, tab2 + l*GTAB*128, a.epack, w2p, w3p,
                a.wpack + OW1P_OFF,
                cf2b + l*128, intb + l*128, ob1, ow2, ob2, a.gbias, a.out);
        }
        const uint* tmp = xr; xr = xw; xw = (uint*)tmp;
    }
}